// Round 8
// baseline (601.169 us; speedup 1.0000x reference)
//
#include <hip/hip_runtime.h>
#include <cstdint>

#define NN 100000
#define EE 1600000
#define HH 128
#define NREP 8
#define NSEG (NREP * NN)
#define PSZ (NN / 8)                 // 12500 rows per XCD partition
#define FILL_EPT 4
#define FILL_CHUNK (256 * FILL_EPT)  // 1024 edges per block-chunk
#define SCAN_CHUNK 512
#define NSCAN ((NN + SCAN_CHUNK - 1) / SCAN_CHUNK)   // 196

typedef unsigned long long u64;
typedef unsigned short ushort;
typedef __attribute__((ext_vector_type(8))) short bf16x8;
typedef __attribute__((ext_vector_type(4))) float f32x4;

// ---------- bf16 helpers (RNE, finite values) ----------
__device__ __forceinline__ ushort f2bf(float x) {
    union { float f; unsigned u; } v; v.f = x;
    unsigned r = v.u + 0x7fffu + ((v.u >> 16) & 1u);
    return (ushort)(r >> 16);
}
__device__ __forceinline__ float bf2f(unsigned h16) {
    union { unsigned u; float f; } v; v.u = h16 << 16; return v.f;
}
__device__ __forceinline__ void unpack8(uint4 q, float* v) {
    v[0] = bf2f(q.x & 0xffffu); v[1] = bf2f(q.x >> 16);
    v[2] = bf2f(q.y & 0xffffu); v[3] = bf2f(q.y >> 16);
    v[4] = bf2f(q.z & 0xffffu); v[5] = bf2f(q.z >> 16);
    v[6] = bf2f(q.w & 0xffffu); v[7] = bf2f(q.w >> 16);
}

// ---------- monotone float<->uint encoding for atomicMax on floats ----------
__device__ __forceinline__ unsigned encf(float f) {
    int b = __float_as_int(f);
    return (b >= 0) ? ((unsigned)b | 0x80000000u) : ~(unsigned)b;
}
__device__ __forceinline__ float decf(unsigned u) {
    return (u & 0x80000000u) ? __int_as_float((int)(u & 0x7fffffffu))
                             : __int_as_float((int)(~u));
}
#define ENC_NEG_INF 0x007FFFFFu  // encf(-inf)

// ---------- init: zero replica histograms + small accumulators ----------
__global__ void k_init(u64* __restrict__ cnt64, float* __restrict__ meansum,
                       unsigned* __restrict__ maxenc, unsigned* __restrict__ lmaxenc,
                       float* __restrict__ esum) {
    int i = blockIdx.x * blockDim.x + threadIdx.x;
    if (i < NSEG) cnt64[i] = 0ull;
    if (i < NREP * HH) { meansum[i] = 0.f; maxenc[i] = ENC_NEG_INF; }
    if (i == 0) { lmaxenc[0] = ENC_NEG_INF; esum[0] = 0.f; }
}

// ---------- pre-transpose weights to bf16 Wt[n][k] ----------
__global__ void k_prep(const float* __restrict__ w0, const float* __restrict__ w1,
                       const float* __restrict__ w2, ushort* __restrict__ wt) {
    int idx = blockIdx.x * blockDim.x + threadIdx.x;
    if (idx >= 3 * HH * HH) return;
    int mat = idx >> 14;
    int e = idx & 16383;
    int n = e >> 7, k = e & 127;
    const float* src = (mat == 0) ? w0 : (mat == 1) ? w1 : w2;
    wt[idx] = f2bf(src[k * HH + n]);
}

// ---------- per-replica 64-bit packed histogram: count<<40 | fix30(weight) ----------
__global__ void k_deg(const int* __restrict__ rows, const float* __restrict__ ea,
                      u64* __restrict__ cnt64) {
    int e = blockIdx.x * blockDim.x + threadIdx.x;
    if (e >= EE) return;
    int rep = blockIdx.x & (NREP - 1);
    u64 pk = (1ull << 40) | (u64)(ea[e] * 1073741824.0f + 0.5f);
    atomicAdd(&cnt64[(size_t)rep * NN + rows[e]], pk);
}

// ---------- reduce replicas -> count, dis ----------
__global__ void k_red(const u64* __restrict__ cnt64, int* __restrict__ count,
                      float* __restrict__ dis) {
    int i = blockIdx.x * blockDim.x + threadIdx.x;
    if (i >= NN) return;
    u64 s = 0;
#pragma unroll
    for (int r = 0; r < NREP; ++r) s += cnt64[(size_t)r * NN + i];
    count[i] = (int)(s >> 40);
    float deg = 1.0f + (float)(s & ((1ull << 40) - 1)) * (1.0f / 1073741824.0f);
    dis[i] = rsqrtf(deg);
}

// ---------- exclusive scan of count -> base (3 kernels) ----------
__global__ void k_scan1(const int* __restrict__ cnt, int* __restrict__ out,
                        int* __restrict__ bsum) {
    int b = blockIdx.x, t = threadIdx.x;
    int i0 = b * SCAN_CHUNK + t * 2;
    int c0 = (i0 < NN) ? cnt[i0] : 0;
    int c1 = (i0 + 1 < NN) ? cnt[i0 + 1] : 0;
    int s = c0 + c1;
    int lane = t & 63, w = t >> 6;
    int v = s;
#pragma unroll
    for (int off = 1; off < 64; off <<= 1) {
        int u = __shfl_up(v, off, 64);
        if (lane >= off) v += u;
    }
    __shared__ int wsum[4];
    if (lane == 63) wsum[w] = v;
    __syncthreads();
    int wadd = 0;
    for (int j = 0; j < w; ++j) wadd += wsum[j];
    int incl = v + wadd;
    int excl = incl - s;
    if (i0 < NN) out[i0] = excl;
    if (i0 + 1 < NN) out[i0 + 1] = excl + c0;
    if (t == 255) bsum[b] = incl;
}

__global__ void k_scan2(int* __restrict__ bsum) {
    __shared__ int tmp[256];
    int t = threadIdx.x;
    int v = (t < NSCAN) ? bsum[t] : 0;
    tmp[t] = v;
    __syncthreads();
    for (int off = 1; off < 256; off <<= 1) {
        int u = (t >= off) ? tmp[t - off] : 0;
        __syncthreads();
        tmp[t] += u;
        __syncthreads();
    }
    if (t < NSCAN) bsum[t] = tmp[t] - v;  // exclusive
}

__global__ void k_scan3(int* __restrict__ out, const int* __restrict__ bsum) {
    int i = blockIdx.x * blockDim.x + threadIdx.x;
    if (i < NN) out[i] += bsum[i / SCAN_CHUNK];
    if (i == 0) out[NN] = EE;   // sentinel
}

// ---------- copy base -> mutable fillptr ----------
__global__ void k_copy(const int* __restrict__ base, int* __restrict__ fillptr) {
    int i = blockIdx.x * blockDim.x + threadIdx.x;
    if (i < NN) fillptr[i] = base[i];
}

// ---------- fill CSR: XCD-partitioned by row range; row-major 4B entries ----------
// block b: partition p=b&7 (rows [p*PSZ,(p+1)*PSZ)), edge chunk b>>3.
// csre region of partition p is contiguous and written only by blocks with b&7==p.
__global__ __launch_bounds__(256) void k_fill(const int* __restrict__ rows,
                                              const int* __restrict__ cols,
                                              const float* __restrict__ ea,
                                              int* __restrict__ fillptr,
                                              unsigned* __restrict__ csre) {
    int b = blockIdx.x;
    int p = b & 7;
    int e0 = (b >> 3) * FILL_CHUNK + threadIdx.x * FILL_EPT;
    const int plo = p * PSZ;
    int4 r4;
    if (e0 + 3 < EE) {
        r4 = *(const int4*)(rows + e0);
    } else {
        r4.x = (e0 < EE) ? rows[e0] : -1;
        r4.y = (e0 + 1 < EE) ? rows[e0 + 1] : -1;
        r4.z = (e0 + 2 < EE) ? rows[e0 + 2] : -1;
        r4.w = (e0 + 3 < EE) ? rows[e0 + 3] : -1;
    }
    int rr[4] = {r4.x, r4.y, r4.z, r4.w};
#pragma unroll
    for (int j = 0; j < 4; ++j) {
        int r = rr[j];
        if ((unsigned)(r - plo) < (unsigned)PSZ) {
            int e = e0 + j;
            unsigned q = (unsigned)(ea[e] * 32767.0f + 0.5f);
            int slot = atomicAdd(&fillptr[r], 1);
            csre[slot] = ((unsigned)cols[e] << 15) | q;
        }
    }
}

// ---------- gather: wave per node, 4 groups x 16 lanes; pre-scaled bf16 rows ----------
// hW rows are h'[c] = dis[c]*h[c]; edge term = (ea*dis[node]) * h'[c];
// self-loop = dis[node] * h'[node]. Output agg = msgsum + bias (fp32).
__global__ __launch_bounds__(256) void k_gather(const ushort* __restrict__ hW,
                                                const unsigned* __restrict__ csre,
                                                const int* __restrict__ base,
                                                const float* __restrict__ dis,
                                                const float* __restrict__ bias,
                                                float* __restrict__ agg) {
    int node = (blockIdx.x * 256 + threadIdx.x) >> 6;
    if (node >= NN) return;
    int lane = threadIdx.x & 63;
    int g = lane >> 4, l = lane & 15;
    int f = l * 8;
    int lo = base[node], hi = base[node + 1];
    float disn = dis[node];
    float wk = disn * (1.0f / 32767.0f);
    float acc[8];
#pragma unroll
    for (int j = 0; j < 8; ++j) acc[j] = 0.f;
    if (g == 0) {  // self-loop
        uint4 q = *(const uint4*)(hW + (size_t)node * HH + f);
        float v[8]; unpack8(q, v);
#pragma unroll
        for (int j = 0; j < 8; ++j) acc[j] = disn * v[j];
    }
    int e = lo + g;
    for (; e + 4 < hi; e += 8) {
        unsigned p0 = csre[e];
        unsigned p1 = csre[e + 4];
        float w0 = (float)(p0 & 0x7fffu) * wk;
        float w1 = (float)(p1 & 0x7fffu) * wk;
        uint4 q0 = *(const uint4*)(hW + (size_t)(p0 >> 15) * HH + f);
        uint4 q1 = *(const uint4*)(hW + (size_t)(p1 >> 15) * HH + f);
        float v0[8], v1[8];
        unpack8(q0, v0); unpack8(q1, v1);
#pragma unroll
        for (int j = 0; j < 8; ++j) acc[j] += w0 * v0[j] + w1 * v1[j];
    }
    if (e < hi) {
        unsigned p0 = csre[e];
        float w0 = (float)(p0 & 0x7fffu) * wk;
        uint4 q0 = *(const uint4*)(hW + (size_t)(p0 >> 15) * HH + f);
        float v0[8]; unpack8(q0, v0);
#pragma unroll
        for (int j = 0; j < 8; ++j) acc[j] += w0 * v0[j];
    }
#pragma unroll
    for (int j = 0; j < 8; ++j) {
        acc[j] += __shfl_xor(acc[j], 16, 64);
        acc[j] += __shfl_xor(acc[j], 32, 64);
    }
    if (g == 0) {
        float4 b0 = *(const float4*)(bias + f);
        float4 b1 = *(const float4*)(bias + f + 4);
        float* dst = agg + (size_t)node * HH + f;
        *(float4*)dst = make_float4(acc[0] + b0.x, acc[1] + b0.y, acc[2] + b0.z, acc[3] + b0.w);
        *(float4*)(dst + 4) = make_float4(acc[4] + b1.x, acc[5] + b1.y, acc[6] + b1.z, acc[7] + b1.w);
    }
}

// ---------- MFMA GEMM: 64x128 tile, K=128, bf16 inputs, fp32 acc ----------
// MODE 0: C_bf16[row] = dis[row] * (A @ W)[row]          (A fp32, no relu)
// MODE 1: C_bf16[row] = dis[row] * (relu(A) @ W)[row]
// MODE 2: heads: logits = relu(relu(A)@W1 + b1) @ w2 + b2, plus mean/masked-max of relu(A)
template <int MODE>
__global__ __launch_bounds__(256) void k_mfma(const float* __restrict__ A,
                                              const ushort* __restrict__ Wt,
                                              ushort* __restrict__ C,
                                              const float* __restrict__ dis,
                                              const float* __restrict__ b1,
                                              const float* __restrict__ w2v,
                                              const float* __restrict__ b2,
                                              const int* __restrict__ ready,
                                              float* __restrict__ logits,
                                              float* __restrict__ meansum,
                                              unsigned* __restrict__ maxenc,
                                              unsigned* __restrict__ lmaxenc, int n) {
    __shared__ ushort As[64 * HH];   // 16 KB, swizzled: elem(m,k) at m*128 + ((k>>3)^(m&15))*8 + (k&7)
    __shared__ int rdy[64];
    __shared__ unsigned slmax;
    const int t = threadIdx.x;
    const int rb = blockIdx.x * 64;
    if (MODE == 2) {
        if (t < 64) rdy[t] = (rb + t < n) ? ready[rb + t] : 0;
        if (t == 0) slmax = ENC_NEG_INF;
    }
    // stage A tile (bf16, swizzled)
#pragma unroll
    for (int i = 0; i < 4; ++i) {
        int m = i * 16 + (t >> 4);
        int k = (t & 15) * 8;
        float4 v0 = make_float4(0.f, 0.f, 0.f, 0.f), v1 = v0;
        if (rb + m < n) {
            const float* src = A + (size_t)(rb + m) * HH + k;
            v0 = *(const float4*)src;
            v1 = *(const float4*)(src + 4);
            if (MODE >= 1) {
                v0.x = fmaxf(v0.x, 0.f); v0.y = fmaxf(v0.y, 0.f);
                v0.z = fmaxf(v0.z, 0.f); v0.w = fmaxf(v0.w, 0.f);
                v1.x = fmaxf(v1.x, 0.f); v1.y = fmaxf(v1.y, 0.f);
                v1.z = fmaxf(v1.z, 0.f); v1.w = fmaxf(v1.w, 0.f);
            }
        }
        ushort pk[8];
        pk[0] = f2bf(v0.x); pk[1] = f2bf(v0.y); pk[2] = f2bf(v0.z); pk[3] = f2bf(v0.w);
        pk[4] = f2bf(v1.x); pk[5] = f2bf(v1.y); pk[6] = f2bf(v1.z); pk[7] = f2bf(v1.w);
        int gsw = (t & 15) ^ (m & 15);
        *(uint4*)(As + m * HH + gsw * 8) = *(uint4*)pk;
    }
    __syncthreads();

    const int wave = t >> 6, lane = t & 63;
    const int cl = lane & 15;       // column-within-tile / A row
    const int kq = lane >> 4;       // k quad
    const int m0 = wave * 16;

    f32x4 acc[8];
#pragma unroll
    for (int c = 0; c < 8; ++c) acc[c] = (f32x4){0.f, 0.f, 0.f, 0.f};

    const int am = m0 + cl;
#pragma unroll
    for (int kk = 0; kk < 4; ++kk) {
        int g = kk * 4 + kq;
        bf16x8 a = *(const bf16x8*)(As + am * HH + ((g ^ cl) * 8));
#pragma unroll
        for (int c = 0; c < 8; ++c) {
            bf16x8 b = *(const bf16x8*)(Wt + (size_t)(c * 16 + cl) * HH + kk * 32 + kq * 8);
            acc[c] = __builtin_amdgcn_mfma_f32_16x16x32_bf16(a, b, acc[c], 0, 0, 0);
        }
    }

    if (MODE < 2) {
        // store C bf16 pre-scaled by dis[row]: D row = m0 + kq*4 + r, col = c*16 + cl
#pragma unroll
        for (int r = 0; r < 4; ++r) {
            int row = rb + m0 + kq * 4 + r;
            if (row < n) {
                float dsc = dis[row];
#pragma unroll
                for (int c = 0; c < 8; ++c)
                    C[(size_t)row * HH + c * 16 + cl] = f2bf(acc[c][r] * dsc);
            }
        }
    } else {
        // heads epilogue
        float b1c[8], w2c[8];
#pragma unroll
        for (int c = 0; c < 8; ++c) { b1c[c] = b1[c * 16 + cl]; w2c[c] = w2v[c * 16 + cl]; }
        const float b2s = b2[0];
        unsigned mylmax = ENC_NEG_INF;
#pragma unroll
        for (int r = 0; r < 4; ++r) {
            float s = 0.f;
#pragma unroll
            for (int c = 0; c < 8; ++c)
                s += fmaxf(acc[c][r] + b1c[c], 0.f) * w2c[c];
            s += __shfl_xor(s, 1, 64);
            s += __shfl_xor(s, 2, 64);
            s += __shfl_xor(s, 4, 64);
            s += __shfl_xor(s, 8, 64);
            if (cl == 0) {
                int rloc = m0 + kq * 4 + r;
                int row = rb + rloc;
                if (row < n) {
                    float lg = s + b2s;
                    logits[row] = lg;
                    if (rdy[rloc] > 0) {
                        unsigned e = encf(lg);
                        if (e > mylmax) mylmax = e;
                    }
                }
            }
        }
        if (cl == 0 && mylmax != ENC_NEG_INF) atomicMax(&slmax, mylmax);

        // mean / masked-max of h = relu(A) (bf16 tile), per feature
        int lim = min(64, n - rb);
        if (t < HH) {
            int f = t, gf = f >> 3, fo = f & 7;
            float sum = 0.f, mx = -3.4e38f;
            for (int m = 0; m < lim; ++m) {
                float v = bf2f(As[m * HH + ((gf ^ (m & 15)) * 8) + fo]);
                sum += v;
                if (rdy[m] > 0) mx = fmaxf(mx, v);
            }
            int rep = blockIdx.x & (NREP - 1);
            atomicAdd(&meansum[rep * HH + f], sum);
            if (mx > -3.0e38f) atomicMax(&maxenc[rep * HH + f], encf(mx));
        }
        __syncthreads();
        if (t == 0 && slmax != ENC_NEG_INF) atomicMax(lmaxenc, slmax);
    }
}

// ---------- small finalize: fc, pass-MLP, v, global max M ----------
__global__ void k_fin1(const float* __restrict__ meansum, const unsigned* __restrict__ maxenc,
                       const unsigned* __restrict__ lmaxenc,
                       const float* __restrict__ val_w, const float* __restrict__ val_b,
                       const float* __restrict__ pe, const float* __restrict__ cl_w,
                       const float* __restrict__ cl_b, const float* __restrict__ pw1,
                       const float* __restrict__ pb1, const float* __restrict__ pw2,
                       const float* __restrict__ pb2, float* __restrict__ scal,
                       float* __restrict__ d_out) {
    __shared__ float xp[144];
    __shared__ float msum[HH];
    __shared__ float zp[HH];
    int t = threadIdx.x;
    if (t < HH) {
        float s = 0.f;
        unsigned mx = ENC_NEG_INF;
#pragma unroll
        for (int r = 0; r < NREP; ++r) {
            s += meansum[r * HH + t];
            unsigned e = maxenc[r * HH + t];
            if (e > mx) mx = e;
        }
        msum[t] = s;
        xp[t] = decf(mx);
    } else if (t < 144) {
        int c = t - HH;
        float s = cl_b[c];
        for (int k = 0; k < 30; ++k) s += pe[k] * cl_w[k * 16 + c];
        xp[t] = s;
    }
    __syncthreads();
    if (t < HH) {
        float s = pb1[t];
        for (int k = 0; k < 144; ++k) s += xp[k] * pw1[k * HH + t];
        zp[t] = fmaxf(s, 0.f);
    }
    __syncthreads();
    if (t < 64) {
        float s1 = zp[t] * pw2[t] + zp[t + 64] * pw2[t + 64];
        float s2 = msum[t] * val_w[t] + msum[t + 64] * val_w[t + 64];
#pragma unroll
        for (int off = 32; off > 0; off >>= 1) {
            s1 += __shfl_xor(s1, off, 64);
            s2 += __shfl_xor(s2, off, 64);
        }
        if (t == 0) {
            float xpass = s1 + pb2[0];
            float v = s2 * (1.0f / NN) + val_b[0];
            float M = fmaxf(decf(lmaxenc[0]), xpass);
            scal[0] = M;
            scal[1] = expf(xpass - M);
            d_out[NN + 1] = v;
        }
    }
}

// ---------- exp pass: unnormalized probs + sum ----------
__global__ __launch_bounds__(256) void k_exp(const float* __restrict__ logits,
                                             const int* __restrict__ ready,
                                             const float* __restrict__ scal,
                                             float* __restrict__ d_out,
                                             float* __restrict__ esum) {
    __shared__ float warr[4];
    int t = threadIdx.x;
    int i = blockIdx.x * 256 + t;
    float M = scal[0];
    float p = 0.f;
    if (i < NN) {
        if (ready[i] > 0) p = expf(logits[i] - M);
        d_out[i] = p;
    }
    float s = p;
#pragma unroll
    for (int off = 32; off > 0; off >>= 1) s += __shfl_xor(s, off, 64);
    if ((t & 63) == 0) warr[t >> 6] = s;
    __syncthreads();
    if (t == 0) atomicAdd(esum, warr[0] + warr[1] + warr[2] + warr[3]);
}

// ---------- normalize ----------
__global__ void k_scale(const float* __restrict__ esum, const float* __restrict__ scal,
                        float* __restrict__ d_out) {
    int i = blockIdx.x * blockDim.x + threadIdx.x;
    float inv = 1.0f / (esum[0] + scal[1]);
    if (i < NN) d_out[i] *= inv;
    else if (i == NN) d_out[NN] = scal[1] * inv;
}

extern "C" void kernel_launch(void* const* d_in, const int* in_sizes, int n_in,
                              void* d_out, int out_size, void* d_ws, size_t ws_size,
                              hipStream_t stream) {
    const float* x      = (const float*)d_in[0];
    const int*   edges  = (const int*)d_in[1];
    const float* eattr  = (const float*)d_in[2];
    const int*   ready  = (const int*)d_in[3];
    const float* pe     = (const float*)d_in[4];
    const float* gcn_w  = (const float*)d_in[5];
    const float* gcn_b  = (const float*)d_in[6];
    const float* mlp_w1 = (const float*)d_in[7];
    const float* mlp_b1 = (const float*)d_in[8];
    const float* mlp_w2 = (const float*)d_in[9];
    const float* mlp_b2 = (const float*)d_in[10];
    const float* val_w  = (const float*)d_in[11];
    const float* val_b  = (const float*)d_in[12];
    const float* cl_w   = (const float*)d_in[13];
    const float* cl_b   = (const float*)d_in[14];
    const float* pw1    = (const float*)d_in[15];
    const float* pb1    = (const float*)d_in[16];
    const float* pw2    = (const float*)d_in[17];
    const float* pb2    = (const float*)d_in[18];

    const int* rows = edges;
    const int* cols = edges + EE;

    // workspace layout (~85 MB)
    float* ws      = (float*)d_ws;
    float* dis     = ws;                          // N
    float* logits  = ws + NN;                     // N
    int*   count   = (int*)(ws + 2 * (size_t)NN); // N
    int*   base    = count + NN;                  // N+1 (sentinel)
    int*   bsum    = base + NN + 1;               // 256
    float* bufB    = (float*)(bsum + 256 + 3);    // N*128 fp32 (gather out / gemm in)
    ushort* bufH   = (ushort*)(bufB + (size_t)NN * HH);  // N*128 bf16 (pre-scaled h')
    unsigned* csre = (unsigned*)(bufH + (size_t)NN * HH); // E x 4B packed (col<<15|ea15)
    float* meansum = (float*)(csre + EE);         // NREP*128
    unsigned* maxenc  = (unsigned*)(meansum + NREP * HH);  // NREP*128
    unsigned* lmaxenc = maxenc + NREP * HH;
    float* esum    = (float*)(lmaxenc + 1);
    float* scal    = esum + 1;                    // 2
    ushort* wt     = (ushort*)(scal + 2);         // 3*128*128 bf16 transposed weights

    // aliases (lifetime-disjoint):
    //  cnt64 (NSEG u64 = 6.4MB, used k_init..k_red) aliases csre (E*4B = 6.4MB, written by k_fill later)
    //  fillptr (N int, used k_copy..k_fill) aliases bufB (written first by gather0, later)
    u64* cnt64   = (u64*)csre;
    int* fillptr = (int*)bufB;

    float* out = (float*)d_out;

    const int nb = (NN + 255) / 256;
    const int gb = (NN + 63) / 64;
    const int eb = (EE + 255) / 256;
    const int ab = (NN * 64 + 255) / 256;   // gather: wave per node
    const int ib = (NSEG + 255) / 256;
    const int fb = ((EE + FILL_CHUNK - 1) / FILL_CHUNK) * 8;  // fill: 8 partition-passes

    k_init<<<ib, 256, 0, stream>>>(cnt64, meansum, maxenc, lmaxenc, esum);
    k_prep<<<(3 * HH * HH + 255) / 256, 256, 0, stream>>>(gcn_w, gcn_w + HH * HH, mlp_w1, wt);
    k_deg<<<eb, 256, 0, stream>>>(rows, eattr, cnt64);
    k_red<<<nb, 256, 0, stream>>>(cnt64, count, dis);

    // CSR build (row-major csre, XCD-partitioned fill)
    k_scan1<<<NSCAN, 256, 0, stream>>>(count, base, bsum);
    k_scan2<<<1, 256, 0, stream>>>(bsum);
    k_scan3<<<nb, 256, 0, stream>>>(base, bsum);
    k_copy<<<nb, 256, 0, stream>>>(base, fillptr);
    k_fill<<<fb, 256, 0, stream>>>(rows, cols, eattr, fillptr, csre);

    // layer 0
    k_mfma<0><<<gb, 256, 0, stream>>>(x, wt, bufH, dis, nullptr, nullptr, nullptr, nullptr,
                                      nullptr, nullptr, nullptr, nullptr, NN);
    k_gather<<<ab, 256, 0, stream>>>(bufH, csre, base, dis, gcn_b, bufB);

    // layer 1 (relu applied on staging of bufB)
    k_mfma<1><<<gb, 256, 0, stream>>>(bufB, wt + HH * HH, bufH, dis, nullptr, nullptr, nullptr,
                                      nullptr, nullptr, nullptr, nullptr, nullptr, NN);
    k_gather<<<ab, 256, 0, stream>>>(bufH, csre, base, dis, gcn_b + HH, bufB);

    // heads
    k_mfma<2><<<gb, 256, 0, stream>>>(bufB, wt + 2 * HH * HH, nullptr, nullptr, mlp_b1, mlp_w2,
                                      mlp_b2, ready, logits, meansum, maxenc, lmaxenc, NN);
    k_fin1<<<1, 256, 0, stream>>>(meansum, maxenc, lmaxenc, val_w, val_b, pe, cl_w, cl_b,
                                  pw1, pb1, pw2, pb2, scal, out);
    k_exp<<<nb, 256, 0, stream>>>(logits, ready, scal, out, esum);
    k_scale<<<(NN + 1 + 255) / 256, 256, 0, stream>>>(esum, scal, out);
}

// Round 9
// 537.334 us; speedup vs baseline: 1.1188x; 1.1188x over previous
//
#include <hip/hip_runtime.h>
#include <cstdint>

#define NN 100000
#define EE 1600000
#define HH 128
#define NREP 8
#define NSEG (NREP * NN)
#define PSZ (NN / 8)                 // 12500 rows per XCD partition
#define FILL_EPT 4
#define FILL_CHUNK (256 * FILL_EPT)  // 1024 edges per block-chunk
#define SCAN_CHUNK 512
#define NSCAN ((NN + SCAN_CHUNK - 1) / SCAN_CHUNK)   // 196

typedef unsigned long long u64;
typedef unsigned short ushort;
typedef unsigned char uchar;
typedef __attribute__((ext_vector_type(8))) short bf16x8;
typedef __attribute__((ext_vector_type(4))) float f32x4;
typedef __attribute__((ext_vector_type(2))) float f32x2;

// ---------- bf16 helpers (RNE, finite values) ----------
__device__ __forceinline__ ushort f2bf(float x) {
    union { float f; unsigned u; } v; v.f = x;
    unsigned r = v.u + 0x7fffu + ((v.u >> 16) & 1u);
    return (ushort)(r >> 16);
}
__device__ __forceinline__ float bf2f(unsigned h16) {
    union { unsigned u; float f; } v; v.u = h16 << 16; return v.f;
}

// ---------- fp8 e4m3 helpers (HW cvt) ----------
__device__ __forceinline__ uchar f2fp8(float a) {
    return (uchar)(__builtin_amdgcn_cvt_pk_fp8_f32(a, a, 0, false) & 0xff);
}
__device__ __forceinline__ void unpack8_fp8(uint2 q, float* v) {
    f32x2 a = __builtin_amdgcn_cvt_pk_f32_fp8(q.x, false);
    f32x2 b = __builtin_amdgcn_cvt_pk_f32_fp8(q.x, true);
    f32x2 c = __builtin_amdgcn_cvt_pk_f32_fp8(q.y, false);
    f32x2 d = __builtin_amdgcn_cvt_pk_f32_fp8(q.y, true);
    v[0] = a[0]; v[1] = a[1]; v[2] = b[0]; v[3] = b[1];
    v[4] = c[0]; v[5] = c[1]; v[6] = d[0]; v[7] = d[1];
}

// ---------- monotone float<->uint encoding for atomicMax on floats ----------
__device__ __forceinline__ unsigned encf(float f) {
    int b = __float_as_int(f);
    return (b >= 0) ? ((unsigned)b | 0x80000000u) : ~(unsigned)b;
}
__device__ __forceinline__ float decf(unsigned u) {
    return (u & 0x80000000u) ? __int_as_float((int)(u & 0x7fffffffu))
                             : __int_as_float((int)(~u));
}
#define ENC_NEG_INF 0x007FFFFFu  // encf(-inf)

// ---------- small init: per-rep head accumulators ----------
__global__ void k_init(float* __restrict__ meansum, unsigned* __restrict__ maxenc,
                       unsigned* __restrict__ lmaxenc, float* __restrict__ esum) {
    int i = blockIdx.x * blockDim.x + threadIdx.x;
    if (i < NREP * HH) { meansum[i] = 0.f; maxenc[i] = ENC_NEG_INF; }
    if (i == 0) { lmaxenc[0] = ENC_NEG_INF; esum[0] = 0.f; }
}

// ---------- pre-transpose weights to bf16 Wt[n][k] ----------
__global__ void k_prep(const float* __restrict__ w0, const float* __restrict__ w1,
                       const float* __restrict__ w2, ushort* __restrict__ wt) {
    int idx = blockIdx.x * blockDim.x + threadIdx.x;
    if (idx >= 3 * HH * HH) return;
    int mat = idx >> 14;
    int e = idx & 16383;
    int n = e >> 7, k = e & 127;
    const float* src = (mat == 0) ? w0 : (mat == 1) ? w1 : w2;
    wt[idx] = f2bf(src[k * HH + n]);
}

// ---------- per-replica 64-bit packed histogram: count<<40 | fix30(weight) ----------
__global__ void k_deg(const int* __restrict__ rows, const float* __restrict__ ea,
                      u64* __restrict__ cnt64) {
    int e = blockIdx.x * blockDim.x + threadIdx.x;
    if (e >= EE) return;
    int rep = blockIdx.x & (NREP - 1);
    u64 pk = (1ull << 40) | (u64)(ea[e] * 1073741824.0f + 0.5f);
    atomicAdd(&cnt64[(size_t)rep * NN + rows[e]], pk);
}

// ---------- reduce replicas -> count, dis ----------
__global__ void k_red(const u64* __restrict__ cnt64, int* __restrict__ count,
                      float* __restrict__ dis) {
    int i = blockIdx.x * blockDim.x + threadIdx.x;
    if (i >= NN) return;
    u64 s = 0;
#pragma unroll
    for (int r = 0; r < NREP; ++r) s += cnt64[(size_t)r * NN + i];
    count[i] = (int)(s >> 40);
    float deg = 1.0f + (float)(s & ((1ull << 40) - 1)) * (1.0f / 1073741824.0f);
    dis[i] = rsqrtf(deg);
}

// ---------- exclusive scan of count -> base (3 kernels) ----------
__global__ void k_scan1(const int* __restrict__ cnt, int* __restrict__ out,
                        int* __restrict__ bsum) {
    int b = blockIdx.x, t = threadIdx.x;
    int i0 = b * SCAN_CHUNK + t * 2;
    int c0 = (i0 < NN) ? cnt[i0] : 0;
    int c1 = (i0 + 1 < NN) ? cnt[i0 + 1] : 0;
    int s = c0 + c1;
    int lane = t & 63, w = t >> 6;
    int v = s;
#pragma unroll
    for (int off = 1; off < 64; off <<= 1) {
        int u = __shfl_up(v, off, 64);
        if (lane >= off) v += u;
    }
    __shared__ int wsum[4];
    if (lane == 63) wsum[w] = v;
    __syncthreads();
    int wadd = 0;
    for (int j = 0; j < w; ++j) wadd += wsum[j];
    int incl = v + wadd;
    int excl = incl - s;
    if (i0 < NN) out[i0] = excl;
    if (i0 + 1 < NN) out[i0 + 1] = excl + c0;
    if (t == 255) bsum[b] = incl;
}

__global__ void k_scan2(int* __restrict__ bsum) {
    __shared__ int tmp[256];
    int t = threadIdx.x;
    int v = (t < NSCAN) ? bsum[t] : 0;
    tmp[t] = v;
    __syncthreads();
    for (int off = 1; off < 256; off <<= 1) {
        int u = (t >= off) ? tmp[t - off] : 0;
        __syncthreads();
        tmp[t] += u;
        __syncthreads();
    }
    if (t < NSCAN) bsum[t] = tmp[t] - v;  // exclusive
}

// ---------- scan finalize + copy to mutable fillptr ----------
__global__ void k_scan3(int* __restrict__ out, const int* __restrict__ bsum,
                        int* __restrict__ fillptr) {
    int i = blockIdx.x * blockDim.x + threadIdx.x;
    if (i < NN) {
        int v = out[i] + bsum[i / SCAN_CHUNK];
        out[i] = v;
        fillptr[i] = v;
    }
    if (i == 0) out[NN] = EE;   // sentinel
}

// ---------- fill CSR: XCD-partitioned by row range; row-major 4B entries ----------
__global__ __launch_bounds__(256) void k_fill(const int* __restrict__ rows,
                                              const int* __restrict__ cols,
                                              const float* __restrict__ ea,
                                              int* __restrict__ fillptr,
                                              unsigned* __restrict__ csre) {
    int b = blockIdx.x;
    int p = b & 7;
    int e0 = (b >> 3) * FILL_CHUNK + threadIdx.x * FILL_EPT;
    const int plo = p * PSZ;
    int4 r4;
    if (e0 + 3 < EE) {
        r4 = *(const int4*)(rows + e0);
    } else {
        r4.x = (e0 < EE) ? rows[e0] : -1;
        r4.y = (e0 + 1 < EE) ? rows[e0 + 1] : -1;
        r4.z = (e0 + 2 < EE) ? rows[e0 + 2] : -1;
        r4.w = (e0 + 3 < EE) ? rows[e0 + 3] : -1;
    }
    int rr[4] = {r4.x, r4.y, r4.z, r4.w};
#pragma unroll
    for (int j = 0; j < 4; ++j) {
        int r = rr[j];
        if ((unsigned)(r - plo) < (unsigned)PSZ) {
            int e = e0 + j;
            unsigned q = (unsigned)(ea[e] * 32767.0f + 0.5f);
            int slot = atomicAdd(&fillptr[r], 1);
            csre[slot] = ((unsigned)cols[e] << 15) | q;
        }
    }
}

// ---------- gather: wave per node, 4 groups x 16 lanes; fp8 rows, batched prefetch ----------
// hW rows are fp8(dis[c]*h[c]); edge term = (ea*dis[node]) * h'[c]; self = dis[node]*h'[node].
__global__ __launch_bounds__(256) void k_gather(const uchar* __restrict__ hW,
                                                const unsigned* __restrict__ csre,
                                                const int* __restrict__ base,
                                                const float* __restrict__ dis,
                                                const float* __restrict__ bias,
                                                float* __restrict__ agg) {
    int node = (blockIdx.x * 256 + threadIdx.x) >> 6;
    if (node >= NN) return;
    int lane = threadIdx.x & 63;
    int g = lane >> 4, l = lane & 15;
    int f = l * 8;                     // byte offset within 128B row
    int lo = base[node], hi = base[node + 1];
    float disn = dis[node];
    float wk = disn * (1.0f / 32767.0f);
    const unsigned SELF = (unsigned)node << 15;  // weight bits = 0
    float acc[8];
#pragma unroll
    for (int j = 0; j < 8; ++j) acc[j] = 0.f;
    if (g == 0) {  // self-loop
        uint2 q = *(const uint2*)(hW + (size_t)node * HH + f);
        float v[8]; unpack8_fp8(q, v);
#pragma unroll
        for (int j = 0; j < 8; ++j) acc[j] = disn * v[j];
    }
    for (int eb = lo + g; eb < hi; eb += 16) {
        unsigned pp[4];
#pragma unroll
        for (int j = 0; j < 4; ++j) {
            int e = eb + j * 4;
            pp[j] = (e < hi) ? csre[e] : SELF;
        }
        uint2 qq[4];
#pragma unroll
        for (int j = 0; j < 4; ++j)
            qq[j] = *(const uint2*)(hW + (size_t)(pp[j] >> 15) * HH + f);
#pragma unroll
        for (int j = 0; j < 4; ++j) {
            float w = (float)(pp[j] & 0x7fffu) * wk;
            float v[8]; unpack8_fp8(qq[j], v);
#pragma unroll
            for (int k = 0; k < 8; ++k) acc[k] += w * v[k];
        }
    }
#pragma unroll
    for (int j = 0; j < 8; ++j) {
        acc[j] += __shfl_xor(acc[j], 16, 64);
        acc[j] += __shfl_xor(acc[j], 32, 64);
    }
    if (g == 0) {
        float4 b0 = *(const float4*)(bias + f);
        float4 b1 = *(const float4*)(bias + f + 4);
        float* dst = agg + (size_t)node * HH + f;
        *(float4*)dst = make_float4(acc[0] + b0.x, acc[1] + b0.y, acc[2] + b0.z, acc[3] + b0.w);
        *(float4*)(dst + 4) = make_float4(acc[4] + b1.x, acc[5] + b1.y, acc[6] + b1.z, acc[7] + b1.w);
    }
}

// ---------- MFMA GEMM: 64x128 tile, K=128, bf16 inputs, fp32 acc ----------
// MODE 0: C_fp8[row] = fp8(dis[row] * (A @ W)[row])          (A fp32, no relu)
// MODE 1: C_fp8[row] = fp8(dis[row] * (relu(A) @ W)[row])
// MODE 2: heads: logits = relu(relu(A)@W1 + b1) @ w2 + b2, plus mean/masked-max of relu(A)
template <int MODE>
__global__ __launch_bounds__(256) void k_mfma(const float* __restrict__ A,
                                              const ushort* __restrict__ Wt,
                                              uchar* __restrict__ C,
                                              const float* __restrict__ dis,
                                              const float* __restrict__ b1,
                                              const float* __restrict__ w2v,
                                              const float* __restrict__ b2,
                                              const int* __restrict__ ready,
                                              float* __restrict__ logits,
                                              float* __restrict__ meansum,
                                              unsigned* __restrict__ maxenc,
                                              unsigned* __restrict__ lmaxenc, int n) {
    __shared__ ushort As[64 * HH];   // 16 KB, swizzled: elem(m,k) at m*128 + ((k>>3)^(m&15))*8 + (k&7)
    __shared__ int rdy[64];
    __shared__ unsigned slmax;
    const int t = threadIdx.x;
    const int rb = blockIdx.x * 64;
    if (MODE == 2) {
        if (t < 64) rdy[t] = (rb + t < n) ? ready[rb + t] : 0;
        if (t == 0) slmax = ENC_NEG_INF;
    }
    // stage A tile (bf16, swizzled)
#pragma unroll
    for (int i = 0; i < 4; ++i) {
        int m = i * 16 + (t >> 4);
        int k = (t & 15) * 8;
        float4 v0 = make_float4(0.f, 0.f, 0.f, 0.f), v1 = v0;
        if (rb + m < n) {
            const float* src = A + (size_t)(rb + m) * HH + k;
            v0 = *(const float4*)src;
            v1 = *(const float4*)(src + 4);
            if (MODE >= 1) {
                v0.x = fmaxf(v0.x, 0.f); v0.y = fmaxf(v0.y, 0.f);
                v0.z = fmaxf(v0.z, 0.f); v0.w = fmaxf(v0.w, 0.f);
                v1.x = fmaxf(v1.x, 0.f); v1.y = fmaxf(v1.y, 0.f);
                v1.z = fmaxf(v1.z, 0.f); v1.w = fmaxf(v1.w, 0.f);
            }
        }
        ushort pk[8];
        pk[0] = f2bf(v0.x); pk[1] = f2bf(v0.y); pk[2] = f2bf(v0.z); pk[3] = f2bf(v0.w);
        pk[4] = f2bf(v1.x); pk[5] = f2bf(v1.y); pk[6] = f2bf(v1.z); pk[7] = f2bf(v1.w);
        int gsw = (t & 15) ^ (m & 15);
        *(uint4*)(As + m * HH + gsw * 8) = *(uint4*)pk;
    }
    __syncthreads();

    const int wave = t >> 6, lane = t & 63;
    const int cl = lane & 15;       // column-within-tile / A row
    const int kq = lane >> 4;       // k quad
    const int m0 = wave * 16;

    f32x4 acc[8];
#pragma unroll
    for (int c = 0; c < 8; ++c) acc[c] = (f32x4){0.f, 0.f, 0.f, 0.f};

    const int am = m0 + cl;
#pragma unroll
    for (int kk = 0; kk < 4; ++kk) {
        int g = kk * 4 + kq;
        bf16x8 a = *(const bf16x8*)(As + am * HH + ((g ^ cl) * 8));
#pragma unroll
        for (int c = 0; c < 8; ++c) {
            bf16x8 b = *(const bf16x8*)(Wt + (size_t)(c * 16 + cl) * HH + kk * 32 + kq * 8);
            acc[c] = __builtin_amdgcn_mfma_f32_16x16x32_bf16(a, b, acc[c], 0, 0, 0);
        }
    }

    if (MODE < 2) {
        // store C fp8 pre-scaled by dis[row]: D row = m0 + kq*4 + r, col = c*16 + cl
#pragma unroll
        for (int r = 0; r < 4; ++r) {
            int row = rb + m0 + kq * 4 + r;
            if (row < n) {
                float dsc = dis[row];
#pragma unroll
                for (int c = 0; c < 8; ++c)
                    C[(size_t)row * HH + c * 16 + cl] = f2fp8(acc[c][r] * dsc);
            }
        }
    } else {
        // heads epilogue
        float b1c[8], w2c[8];
#pragma unroll
        for (int c = 0; c < 8; ++c) { b1c[c] = b1[c * 16 + cl]; w2c[c] = w2v[c * 16 + cl]; }
        const float b2s = b2[0];
        unsigned mylmax = ENC_NEG_INF;
#pragma unroll
        for (int r = 0; r < 4; ++r) {
            float s = 0.f;
#pragma unroll
            for (int c = 0; c < 8; ++c)
                s += fmaxf(acc[c][r] + b1c[c], 0.f) * w2c[c];
            s += __shfl_xor(s, 1, 64);
            s += __shfl_xor(s, 2, 64);
            s += __shfl_xor(s, 4, 64);
            s += __shfl_xor(s, 8, 64);
            if (cl == 0) {
                int rloc = m0 + kq * 4 + r;
                int row = rb + rloc;
                if (row < n) {
                    float lg = s + b2s;
                    logits[row] = lg;
                    if (rdy[rloc] > 0) {
                        unsigned e = encf(lg);
                        if (e > mylmax) mylmax = e;
                    }
                }
            }
        }
        if (cl == 0 && mylmax != ENC_NEG_INF) atomicMax(&slmax, mylmax);

        // mean / masked-max of h = relu(A) (bf16 tile), per feature
        int lim = min(64, n - rb);
        if (t < HH) {
            int f = t, gf = f >> 3, fo = f & 7;
            float sum = 0.f, mx = -3.4e38f;
            for (int m = 0; m < lim; ++m) {
                float v = bf2f(As[m * HH + ((gf ^ (m & 15)) * 8) + fo]);
                sum += v;
                if (rdy[m] > 0) mx = fmaxf(mx, v);
            }
            int rep = blockIdx.x & (NREP - 1);
            atomicAdd(&meansum[rep * HH + f], sum);
            if (mx > -3.0e38f) atomicMax(&maxenc[rep * HH + f], encf(mx));
        }
        __syncthreads();
        if (t == 0 && slmax != ENC_NEG_INF) atomicMax(lmaxenc, slmax);
    }
}

// ---------- small finalize: fc, pass-MLP, v, global max M ----------
__global__ void k_fin1(const float* __restrict__ meansum, const unsigned* __restrict__ maxenc,
                       const unsigned* __restrict__ lmaxenc,
                       const float* __restrict__ val_w, const float* __restrict__ val_b,
                       const float* __restrict__ pe, const float* __restrict__ cl_w,
                       const float* __restrict__ cl_b, const float* __restrict__ pw1,
                       const float* __restrict__ pb1, const float* __restrict__ pw2,
                       const float* __restrict__ pb2, float* __restrict__ scal,
                       float* __restrict__ d_out) {
    __shared__ float xp[144];
    __shared__ float msum[HH];
    __shared__ float zp[HH];
    int t = threadIdx.x;
    if (t < HH) {
        float s = 0.f;
        unsigned mx = ENC_NEG_INF;
#pragma unroll
        for (int r = 0; r < NREP; ++r) {
            s += meansum[r * HH + t];
            unsigned e = maxenc[r * HH + t];
            if (e > mx) mx = e;
        }
        msum[t] = s;
        xp[t] = decf(mx);
    } else if (t < 144) {
        int c = t - HH;
        float s = cl_b[c];
        for (int k = 0; k < 30; ++k) s += pe[k] * cl_w[k * 16 + c];
        xp[t] = s;
    }
    __syncthreads();
    if (t < HH) {
        float s = pb1[t];
        for (int k = 0; k < 144; ++k) s += xp[k] * pw1[k * HH + t];
        zp[t] = fmaxf(s, 0.f);
    }
    __syncthreads();
    if (t < 64) {
        float s1 = zp[t] * pw2[t] + zp[t + 64] * pw2[t + 64];
        float s2 = msum[t] * val_w[t] + msum[t + 64] * val_w[t + 64];
#pragma unroll
        for (int off = 32; off > 0; off >>= 1) {
            s1 += __shfl_xor(s1, off, 64);
            s2 += __shfl_xor(s2, off, 64);
        }
        if (t == 0) {
            float xpass = s1 + pb2[0];
            float v = s2 * (1.0f / NN) + val_b[0];
            float M = fmaxf(decf(lmaxenc[0]), xpass);
            scal[0] = M;
            scal[1] = expf(xpass - M);
            d_out[NN + 1] = v;
        }
    }
}

// ---------- exp pass: unnormalized probs + sum ----------
__global__ __launch_bounds__(256) void k_exp(const float* __restrict__ logits,
                                             const int* __restrict__ ready,
                                             const float* __restrict__ scal,
                                             float* __restrict__ d_out,
                                             float* __restrict__ esum) {
    __shared__ float warr[4];
    int t = threadIdx.x;
    int i = blockIdx.x * 256 + t;
    float M = scal[0];
    float p = 0.f;
    if (i < NN) {
        if (ready[i] > 0) p = expf(logits[i] - M);
        d_out[i] = p;
    }
    float s = p;
#pragma unroll
    for (int off = 32; off > 0; off >>= 1) s += __shfl_xor(s, off, 64);
    if ((t & 63) == 0) warr[t >> 6] = s;
    __syncthreads();
    if (t == 0) atomicAdd(esum, warr[0] + warr[1] + warr[2] + warr[3]);
}

// ---------- normalize ----------
__global__ void k_scale(const float* __restrict__ esum, const float* __restrict__ scal,
                        float* __restrict__ d_out) {
    int i = blockIdx.x * blockDim.x + threadIdx.x;
    float inv = 1.0f / (esum[0] + scal[1]);
    if (i < NN) d_out[i] *= inv;
    else if (i == NN) d_out[NN] = scal[1] * inv;
}

extern "C" void kernel_launch(void* const* d_in, const int* in_sizes, int n_in,
                              void* d_out, int out_size, void* d_ws, size_t ws_size,
                              hipStream_t stream) {
    const float* x      = (const float*)d_in[0];
    const int*   edges  = (const int*)d_in[1];
    const float* eattr  = (const float*)d_in[2];
    const int*   ready  = (const int*)d_in[3];
    const float* pe     = (const float*)d_in[4];
    const float* gcn_w  = (const float*)d_in[5];
    const float* gcn_b  = (const float*)d_in[6];
    const float* mlp_w1 = (const float*)d_in[7];
    const float* mlp_b1 = (const float*)d_in[8];
    const float* mlp_w2 = (const float*)d_in[9];
    const float* mlp_b2 = (const float*)d_in[10];
    const float* val_w  = (const float*)d_in[11];
    const float* val_b  = (const float*)d_in[12];
    const float* cl_w   = (const float*)d_in[13];
    const float* cl_b   = (const float*)d_in[14];
    const float* pw1    = (const float*)d_in[15];
    const float* pb1    = (const float*)d_in[16];
    const float* pw2    = (const float*)d_in[17];
    const float* pb2    = (const float*)d_in[18];

    const int* rows = edges;
    const int* cols = edges + EE;

    // workspace layout (~72 MB)
    float* ws      = (float*)d_ws;
    float* dis     = ws;                          // N
    float* logits  = ws + NN;                     // N
    int*   count   = (int*)(ws + 2 * (size_t)NN); // N
    int*   base    = count + NN;                  // N+1 (sentinel)
    int*   bsum    = base + NN + 1;               // 256
    float* bufB    = (float*)(bsum + 256 + 3);    // N*128 fp32 (gather out / gemm in)
    uchar* bufH    = (uchar*)(bufB + (size_t)NN * HH);   // N*128 fp8 (pre-scaled h')
    unsigned* csre = (unsigned*)(bufH + (size_t)NN * HH); // E x 4B packed (col<<15|ea15)
    float* meansum = (float*)(csre + EE);         // NREP*128
    unsigned* maxenc  = (unsigned*)(meansum + NREP * HH);  // NREP*128
    unsigned* lmaxenc = maxenc + NREP * HH;
    float* esum    = (float*)(lmaxenc + 1);
    float* scal    = esum + 1;                    // 2
    ushort* wt     = (ushort*)(scal + 2);         // 3*128*128 bf16 transposed weights

    // aliases (lifetime-disjoint):
    //  cnt64 (NSEG u64 = 6.4MB, used memset..k_scan1) aliases csre (E*4B = 6.4MB, written by k_fill later)
    //  fillptr (N int, used k_scan3..k_fill) aliases bufB (written first by gather0, later)
    u64* cnt64   = (u64*)csre;
    int* fillptr = (int*)bufB;

    float* out = (float*)d_out;

    const int nb = (NN + 255) / 256;
    const int gb = (NN + 63) / 64;
    const int eb = (EE + 255) / 256;
    const int ab = (NN * 64 + 255) / 256;   // gather: wave per node
    const int fb = ((EE + FILL_CHUNK - 1) / FILL_CHUNK) * 8;  // fill: 8 partition-passes

    hipMemsetAsync(cnt64, 0, (size_t)NSEG * sizeof(u64), stream);
    k_init<<<(NREP * HH + 255) / 256, 256, 0, stream>>>(meansum, maxenc, lmaxenc, esum);
    k_prep<<<(3 * HH * HH + 255) / 256, 256, 0, stream>>>(gcn_w, gcn_w + HH * HH, mlp_w1, wt);
    k_deg<<<eb, 256, 0, stream>>>(rows, eattr, cnt64);
    k_red<<<nb, 256, 0, stream>>>(cnt64, count, dis);

    // CSR build (row-major csre, XCD-partitioned fill)
    k_scan1<<<NSCAN, 256, 0, stream>>>(count, base, bsum);
    k_scan2<<<1, 256, 0, stream>>>(bsum);
    k_scan3<<<nb, 256, 0, stream>>>(base, bsum, fillptr);
    k_fill<<<fb, 256, 0, stream>>>(rows, cols, eattr, fillptr, csre);

    // layer 0
    k_mfma<0><<<gb, 256, 0, stream>>>(x, wt, bufH, dis, nullptr, nullptr, nullptr, nullptr,
                                      nullptr, nullptr, nullptr, nullptr, NN);
    k_gather<<<ab, 256, 0, stream>>>(bufH, csre, base, dis, gcn_b, bufB);

    // layer 1 (relu applied on staging of bufB)
    k_mfma<1><<<gb, 256, 0, stream>>>(bufB, wt + HH * HH, bufH, dis, nullptr, nullptr, nullptr,
                                      nullptr, nullptr, nullptr, nullptr, nullptr, NN);
    k_gather<<<ab, 256, 0, stream>>>(bufH, csre, base, dis, gcn_b + HH, bufB);

    // heads
    k_mfma<2><<<gb, 256, 0, stream>>>(bufB, wt + 2 * HH * HH, nullptr, nullptr, mlp_b1, mlp_w2,
                                      mlp_b2, ready, logits, meansum, maxenc, lmaxenc, NN);
    k_fin1<<<1, 256, 0, stream>>>(meansum, maxenc, lmaxenc, val_w, val_b, pe, cl_w, cl_b,
                                  pw1, pb1, pw2, pb2, scal, out);
    k_exp<<<nb, 256, 0, stream>>>(logits, ready, scal, out, esum);
    k_scale<<<(NN + 1 + 255) / 256, 256, 0, stream>>>(esum, scal, out);
}

// Round 10
// 510.691 us; speedup vs baseline: 1.1772x; 1.0522x over previous
//
#include <hip/hip_runtime.h>
#include <cstdint>

#define NN 100000
#define EE 1600000
#define HH 128
#define NREP 8
#define PSZ (NN / 8)                 // 12500 rows per partition
#define CC 32                        // edge chunks
#define CH (EE / CC)                 // 50000 edges per chunk
#define SCAN_CHUNK 512
#define NSCAN ((NN + SCAN_CHUNK - 1) / SCAN_CHUNK)   // 196

typedef unsigned long long u64;
typedef unsigned short ushort;
typedef unsigned char uchar;
typedef __attribute__((ext_vector_type(8))) short bf16x8;
typedef __attribute__((ext_vector_type(4))) float f32x4;
typedef __attribute__((ext_vector_type(2))) float f32x2;

// ---------- bf16 helpers (RNE, finite values) ----------
__device__ __forceinline__ ushort f2bf(float x) {
    union { float f; unsigned u; } v; v.f = x;
    unsigned r = v.u + 0x7fffu + ((v.u >> 16) & 1u);
    return (ushort)(r >> 16);
}
__device__ __forceinline__ float bf2f(unsigned h16) {
    union { unsigned u; float f; } v; v.u = h16 << 16; return v.f;
}

// ---------- fp8 e4m3 helpers (HW cvt) ----------
__device__ __forceinline__ uchar f2fp8(float a) {
    return (uchar)(__builtin_amdgcn_cvt_pk_fp8_f32(a, a, 0, false) & 0xff);
}
__device__ __forceinline__ void unpack8_fp8(uint2 q, float* v) {
    f32x2 a = __builtin_amdgcn_cvt_pk_f32_fp8(q.x, false);
    f32x2 b = __builtin_amdgcn_cvt_pk_f32_fp8(q.x, true);
    f32x2 c = __builtin_amdgcn_cvt_pk_f32_fp8(q.y, false);
    f32x2 d = __builtin_amdgcn_cvt_pk_f32_fp8(q.y, true);
    v[0] = a[0]; v[1] = a[1]; v[2] = b[0]; v[3] = b[1];
    v[4] = c[0]; v[5] = c[1]; v[6] = d[0]; v[7] = d[1];
}

// ---------- monotone float<->uint encoding for atomicMax on floats ----------
__device__ __forceinline__ unsigned encf(float f) {
    int b = __float_as_int(f);
    return (b >= 0) ? ((unsigned)b | 0x80000000u) : ~(unsigned)b;
}
__device__ __forceinline__ float decf(unsigned u) {
    return (u & 0x80000000u) ? __int_as_float((int)(u & 0x7fffffffu))
                             : __int_as_float((int)(~u));
}
#define ENC_NEG_INF 0x007FFFFFu  // encf(-inf)

// ---------- small init: per-rep head accumulators ----------
__global__ void k_init(float* __restrict__ meansum, unsigned* __restrict__ maxenc,
                       unsigned* __restrict__ lmaxenc, float* __restrict__ esum) {
    int i = blockIdx.x * blockDim.x + threadIdx.x;
    if (i < NREP * HH) { meansum[i] = 0.f; maxenc[i] = ENC_NEG_INF; }
    if (i == 0) { lmaxenc[0] = ENC_NEG_INF; esum[0] = 0.f; }
}

// ---------- pre-transpose weights to bf16 Wt[n][k] ----------
__global__ void k_prep(const float* __restrict__ w0, const float* __restrict__ w1,
                       const float* __restrict__ w2, ushort* __restrict__ wt) {
    int idx = blockIdx.x * blockDim.x + threadIdx.x;
    if (idx >= 3 * HH * HH) return;
    int mat = idx >> 14;
    int e = idx & 16383;
    int n = e >> 7, k = e & 127;
    const float* src = (mat == 0) ? w0 : (mat == 1) ? w1 : w2;
    wt[idx] = f2bf(src[k * HH + n]);
}

// ---------- count: per-(chunk,partition) LDS histogram, unique-owner flush ----------
__global__ __launch_bounds__(256) void k_cnt(const int* __restrict__ rows,
                                             int* __restrict__ cnt) {
    __shared__ int h[PSZ];
    int b = blockIdx.x;
    int c = b >> 3, p = b & 7;
    int plo = p * PSZ;
    for (int j = threadIdx.x; j < PSZ; j += 256) h[j] = 0;
    __syncthreads();
    int e0 = c * CH;
    for (int i = threadIdx.x * 4; i < CH; i += 1024) {
        int4 r4 = *(const int4*)(rows + e0 + i);
        int rr[4] = {r4.x, r4.y, r4.z, r4.w};
#pragma unroll
        for (int j = 0; j < 4; ++j) {
            int r = rr[j] - plo;
            if ((unsigned)r < (unsigned)PSZ) atomicAdd(&h[r], 1);
        }
    }
    __syncthreads();
    int* dst = cnt + (size_t)c * NN + plo;
    for (int j = threadIdx.x; j < PSZ; j += 256) dst[j] = h[j];
}

// ---------- count[r] = sum over chunks ----------
__global__ void k_rowsum(const int* __restrict__ cnt, int* __restrict__ count) {
    int r = blockIdx.x * blockDim.x + threadIdx.x;
    if (r >= NN) return;
    int s = 0;
#pragma unroll 8
    for (int c = 0; c < CC; ++c) s += cnt[(size_t)c * NN + r];
    count[r] = s;
}

// ---------- exclusive scan of count -> base (3 kernels) ----------
__global__ void k_scan1(const int* __restrict__ cnt, int* __restrict__ out,
                        int* __restrict__ bsum) {
    int b = blockIdx.x, t = threadIdx.x;
    int i0 = b * SCAN_CHUNK + t * 2;
    int c0 = (i0 < NN) ? cnt[i0] : 0;
    int c1 = (i0 + 1 < NN) ? cnt[i0 + 1] : 0;
    int s = c0 + c1;
    int lane = t & 63, w = t >> 6;
    int v = s;
#pragma unroll
    for (int off = 1; off < 64; off <<= 1) {
        int u = __shfl_up(v, off, 64);
        if (lane >= off) v += u;
    }
    __shared__ int wsum[4];
    if (lane == 63) wsum[w] = v;
    __syncthreads();
    int wadd = 0;
    for (int j = 0; j < w; ++j) wadd += wsum[j];
    int incl = v + wadd;
    int excl = incl - s;
    if (i0 < NN) out[i0] = excl;
    if (i0 + 1 < NN) out[i0 + 1] = excl + c0;
    if (t == 255) bsum[b] = incl;
}

__global__ void k_scan2(int* __restrict__ bsum) {
    __shared__ int tmp[256];
    int t = threadIdx.x;
    int v = (t < NSCAN) ? bsum[t] : 0;
    tmp[t] = v;
    __syncthreads();
    for (int off = 1; off < 256; off <<= 1) {
        int u = (t >= off) ? tmp[t - off] : 0;
        __syncthreads();
        tmp[t] += u;
        __syncthreads();
    }
    if (t < NSCAN) bsum[t] = tmp[t] - v;  // exclusive
}

__global__ void k_scan3(int* __restrict__ out, const int* __restrict__ bsum) {
    int i = blockIdx.x * blockDim.x + threadIdx.x;
    if (i < NN) out[i] += bsum[i / SCAN_CHUNK];
    if (i == 0) out[NN] = EE;   // sentinel
}

// ---------- per-(chunk,row) fill starts ----------
__global__ void k_makeptr(const int* __restrict__ cnt, const int* __restrict__ base,
                          int* __restrict__ fillptr) {
    int r = blockIdx.x * blockDim.x + threadIdx.x;
    if (r >= NN) return;
    int acc = base[r];
#pragma unroll 8
    for (int c = 0; c < CC; ++c) {
        fillptr[(size_t)c * NN + r] = acc;
        acc += cnt[(size_t)c * NN + r];
    }
}

// ---------- fill CSR: unique (chunk,partition) owner; LDS slot counters ----------
__global__ __launch_bounds__(256) void k_fill(const int* __restrict__ rows,
                                              const int* __restrict__ cols,
                                              const float* __restrict__ ea,
                                              const int* __restrict__ fillptr,
                                              unsigned* __restrict__ csre) {
    __shared__ int nxt[PSZ];
    int b = blockIdx.x;
    int c = b >> 3, p = b & 7;
    int plo = p * PSZ;
    const int* src = fillptr + (size_t)c * NN + plo;
    for (int j = threadIdx.x; j < PSZ; j += 256) nxt[j] = src[j];
    __syncthreads();
    int e0 = c * CH;
    for (int i = threadIdx.x * 4; i < CH; i += 1024) {
        int4 r4 = *(const int4*)(rows + e0 + i);
        int rr[4] = {r4.x, r4.y, r4.z, r4.w};
#pragma unroll
        for (int j = 0; j < 4; ++j) {
            int r = rr[j] - plo;
            if ((unsigned)r < (unsigned)PSZ) {
                int e = e0 + i + j;
                int slot = atomicAdd(&nxt[r], 1);
                unsigned q = (unsigned)(ea[e] * 32767.0f + 0.5f);
                csre[slot] = ((unsigned)cols[e] << 15) | q;
            }
        }
    }
}

// ---------- deg from csre segment sums -> dis ----------
__global__ void k_degsum(const unsigned* __restrict__ csre, const int* __restrict__ base,
                         float* __restrict__ dis) {
    int r = blockIdx.x * blockDim.x + threadIdx.x;
    if (r >= NN) return;
    int lo = base[r], hi = base[r + 1];
    float s = 0.f;
    for (int e = lo; e < hi; ++e) s += (float)(csre[e] & 0x7fffu);
    dis[r] = rsqrtf(1.0f + s * (1.0f / 32767.0f));
}

// ---------- gather: wave per node, 4 groups x 16 lanes; fp8 rows, batched prefetch ----------
__global__ __launch_bounds__(256) void k_gather(const uchar* __restrict__ hW,
                                                const unsigned* __restrict__ csre,
                                                const int* __restrict__ base,
                                                const float* __restrict__ dis,
                                                const float* __restrict__ bias,
                                                float* __restrict__ agg) {
    int node = (blockIdx.x * 256 + threadIdx.x) >> 6;
    if (node >= NN) return;
    int lane = threadIdx.x & 63;
    int g = lane >> 4, l = lane & 15;
    int f = l * 8;                     // byte offset within 128B row
    int lo = base[node], hi = base[node + 1];
    float disn = dis[node];
    float wk = disn * (1.0f / 32767.0f);
    const unsigned SELF = (unsigned)node << 15;  // weight bits = 0
    float acc[8];
#pragma unroll
    for (int j = 0; j < 8; ++j) acc[j] = 0.f;
    if (g == 0) {  // self-loop
        uint2 q = *(const uint2*)(hW + (size_t)node * HH + f);
        float v[8]; unpack8_fp8(q, v);
#pragma unroll
        for (int j = 0; j < 8; ++j) acc[j] = disn * v[j];
    }
    for (int eb = lo + g; eb < hi; eb += 16) {
        unsigned pp[4];
#pragma unroll
        for (int j = 0; j < 4; ++j) {
            int e = eb + j * 4;
            pp[j] = (e < hi) ? csre[e] : SELF;
        }
        uint2 qq[4];
#pragma unroll
        for (int j = 0; j < 4; ++j)
            qq[j] = *(const uint2*)(hW + (size_t)(pp[j] >> 15) * HH + f);
#pragma unroll
        for (int j = 0; j < 4; ++j) {
            float w = (float)(pp[j] & 0x7fffu) * wk;
            float v[8]; unpack8_fp8(qq[j], v);
#pragma unroll
            for (int k = 0; k < 8; ++k) acc[k] += w * v[k];
        }
    }
#pragma unroll
    for (int j = 0; j < 8; ++j) {
        acc[j] += __shfl_xor(acc[j], 16, 64);
        acc[j] += __shfl_xor(acc[j], 32, 64);
    }
    if (g == 0) {
        float4 b0 = *(const float4*)(bias + f);
        float4 b1 = *(const float4*)(bias + f + 4);
        float* dst = agg + (size_t)node * HH + f;
        *(float4*)dst = make_float4(acc[0] + b0.x, acc[1] + b0.y, acc[2] + b0.z, acc[3] + b0.w);
        *(float4*)(dst + 4) = make_float4(acc[4] + b1.x, acc[5] + b1.y, acc[6] + b1.z, acc[7] + b1.w);
    }
}

// ---------- MFMA GEMM: 64x128 tile, K=128, bf16 inputs, fp32 acc ----------
// MODE 0: C_fp8[row] = fp8(dis[row] * (A @ W)[row])          (A fp32, no relu)
// MODE 1: C_fp8[row] = fp8(dis[row] * (relu(A) @ W)[row])
// MODE 2: heads: logits = relu(relu(A)@W1 + b1) @ w2 + b2, plus mean/masked-max of relu(A)
template <int MODE>
__global__ __launch_bounds__(256) void k_mfma(const float* __restrict__ A,
                                              const ushort* __restrict__ Wt,
                                              uchar* __restrict__ C,
                                              const float* __restrict__ dis,
                                              const float* __restrict__ b1,
                                              const float* __restrict__ w2v,
                                              const float* __restrict__ b2,
                                              const int* __restrict__ ready,
                                              float* __restrict__ logits,
                                              float* __restrict__ meansum,
                                              unsigned* __restrict__ maxenc,
                                              unsigned* __restrict__ lmaxenc, int n) {
    __shared__ ushort As[64 * HH];   // 16 KB, swizzled: elem(m,k) at m*128 + ((k>>3)^(m&15))*8 + (k&7)
    __shared__ int rdy[64];
    __shared__ unsigned slmax;
    const int t = threadIdx.x;
    const int rb = blockIdx.x * 64;
    if (MODE == 2) {
        if (t < 64) rdy[t] = (rb + t < n) ? ready[rb + t] : 0;
        if (t == 0) slmax = ENC_NEG_INF;
    }
    // stage A tile (bf16, swizzled)
#pragma unroll
    for (int i = 0; i < 4; ++i) {
        int m = i * 16 + (t >> 4);
        int k = (t & 15) * 8;
        float4 v0 = make_float4(0.f, 0.f, 0.f, 0.f), v1 = v0;
        if (rb + m < n) {
            const float* src = A + (size_t)(rb + m) * HH + k;
            v0 = *(const float4*)src;
            v1 = *(const float4*)(src + 4);
            if (MODE >= 1) {
                v0.x = fmaxf(v0.x, 0.f); v0.y = fmaxf(v0.y, 0.f);
                v0.z = fmaxf(v0.z, 0.f); v0.w = fmaxf(v0.w, 0.f);
                v1.x = fmaxf(v1.x, 0.f); v1.y = fmaxf(v1.y, 0.f);
                v1.z = fmaxf(v1.z, 0.f); v1.w = fmaxf(v1.w, 0.f);
            }
        }
        ushort pk[8];
        pk[0] = f2bf(v0.x); pk[1] = f2bf(v0.y); pk[2] = f2bf(v0.z); pk[3] = f2bf(v0.w);
        pk[4] = f2bf(v1.x); pk[5] = f2bf(v1.y); pk[6] = f2bf(v1.z); pk[7] = f2bf(v1.w);
        int gsw = (t & 15) ^ (m & 15);
        *(uint4*)(As + m * HH + gsw * 8) = *(uint4*)pk;
    }
    __syncthreads();

    const int wave = t >> 6, lane = t & 63;
    const int cl = lane & 15;       // column-within-tile / A row
    const int kq = lane >> 4;       // k quad
    const int m0 = wave * 16;

    f32x4 acc[8];
#pragma unroll
    for (int c = 0; c < 8; ++c) acc[c] = (f32x4){0.f, 0.f, 0.f, 0.f};

    const int am = m0 + cl;
#pragma unroll
    for (int kk = 0; kk < 4; ++kk) {
        int g = kk * 4 + kq;
        bf16x8 a = *(const bf16x8*)(As + am * HH + ((g ^ cl) * 8));
#pragma unroll
        for (int c = 0; c < 8; ++c) {
            bf16x8 b = *(const bf16x8*)(Wt + (size_t)(c * 16 + cl) * HH + kk * 32 + kq * 8);
            acc[c] = __builtin_amdgcn_mfma_f32_16x16x32_bf16(a, b, acc[c], 0, 0, 0);
        }
    }

    if (MODE < 2) {
        // store C fp8 pre-scaled by dis[row]: D row = m0 + kq*4 + r, col = c*16 + cl
#pragma unroll
        for (int r = 0; r < 4; ++r) {
            int row = rb + m0 + kq * 4 + r;
            if (row < n) {
                float dsc = dis[row];
#pragma unroll
                for (int c = 0; c < 8; ++c)
                    C[(size_t)row * HH + c * 16 + cl] = f2fp8(acc[c][r] * dsc);
            }
        }
    } else {
        // heads epilogue
        float b1c[8], w2c[8];
#pragma unroll
        for (int c = 0; c < 8; ++c) { b1c[c] = b1[c * 16 + cl]; w2c[c] = w2v[c * 16 + cl]; }
        const float b2s = b2[0];
        unsigned mylmax = ENC_NEG_INF;
#pragma unroll
        for (int r = 0; r < 4; ++r) {
            float s = 0.f;
#pragma unroll
            for (int c = 0; c < 8; ++c)
                s += fmaxf(acc[c][r] + b1c[c], 0.f) * w2c[c];
            s += __shfl_xor(s, 1, 64);
            s += __shfl_xor(s, 2, 64);
            s += __shfl_xor(s, 4, 64);
            s += __shfl_xor(s, 8, 64);
            if (cl == 0) {
                int rloc = m0 + kq * 4 + r;
                int row = rb + rloc;
                if (row < n) {
                    float lg = s + b2s;
                    logits[row] = lg;
                    if (rdy[rloc] > 0) {
                        unsigned e = encf(lg);
                        if (e > mylmax) mylmax = e;
                    }
                }
            }
        }
        if (cl == 0 && mylmax != ENC_NEG_INF) atomicMax(&slmax, mylmax);

        // mean / masked-max of h = relu(A) (bf16 tile), per feature
        int lim = min(64, n - rb);
        if (t < HH) {
            int f = t, gf = f >> 3, fo = f & 7;
            float sum = 0.f, mx = -3.4e38f;
            for (int m = 0; m < lim; ++m) {
                float v = bf2f(As[m * HH + ((gf ^ (m & 15)) * 8) + fo]);
                sum += v;
                if (rdy[m] > 0) mx = fmaxf(mx, v);
            }
            int rep = blockIdx.x & (NREP - 1);
            atomicAdd(&meansum[rep * HH + f], sum);
            if (mx > -3.0e38f) atomicMax(&maxenc[rep * HH + f], encf(mx));
        }
        __syncthreads();
        if (t == 0 && slmax != ENC_NEG_INF) atomicMax(lmaxenc, slmax);
    }
}

// ---------- small finalize: fc, pass-MLP, v, global max M ----------
__global__ void k_fin1(const float* __restrict__ meansum, const unsigned* __restrict__ maxenc,
                       const unsigned* __restrict__ lmaxenc,
                       const float* __restrict__ val_w, const float* __restrict__ val_b,
                       const float* __restrict__ pe, const float* __restrict__ cl_w,
                       const float* __restrict__ cl_b, const float* __restrict__ pw1,
                       const float* __restrict__ pb1, const float* __restrict__ pw2,
                       const float* __restrict__ pb2, float* __restrict__ scal,
                       float* __restrict__ d_out) {
    __shared__ float xp[144];
    __shared__ float msum[HH];
    __shared__ float zp[HH];
    int t = threadIdx.x;
    if (t < HH) {
        float s = 0.f;
        unsigned mx = ENC_NEG_INF;
#pragma unroll
        for (int r = 0; r < NREP; ++r) {
            s += meansum[r * HH + t];
            unsigned e = maxenc[r * HH + t];
            if (e > mx) mx = e;
        }
        msum[t] = s;
        xp[t] = decf(mx);
    } else if (t < 144) {
        int c = t - HH;
        float s = cl_b[c];
        for (int k = 0; k < 30; ++k) s += pe[k] * cl_w[k * 16 + c];
        xp[t] = s;
    }
    __syncthreads();
    if (t < HH) {
        float s = pb1[t];
        for (int k = 0; k < 144; ++k) s += xp[k] * pw1[k * HH + t];
        zp[t] = fmaxf(s, 0.f);
    }
    __syncthreads();
    if (t < 64) {
        float s1 = zp[t] * pw2[t] + zp[t + 64] * pw2[t + 64];
        float s2 = msum[t] * val_w[t] + msum[t + 64] * val_w[t + 64];
#pragma unroll
        for (int off = 32; off > 0; off >>= 1) {
            s1 += __shfl_xor(s1, off, 64);
            s2 += __shfl_xor(s2, off, 64);
        }
        if (t == 0) {
            float xpass = s1 + pb2[0];
            float v = s2 * (1.0f / NN) + val_b[0];
            float M = fmaxf(decf(lmaxenc[0]), xpass);
            scal[0] = M;
            scal[1] = expf(xpass - M);
            d_out[NN + 1] = v;
        }
    }
}

// ---------- exp pass: unnormalized probs + sum ----------
__global__ __launch_bounds__(256) void k_exp(const float* __restrict__ logits,
                                             const int* __restrict__ ready,
                                             const float* __restrict__ scal,
                                             float* __restrict__ d_out,
                                             float* __restrict__ esum) {
    __shared__ float warr[4];
    int t = threadIdx.x;
    int i = blockIdx.x * 256 + t;
    float M = scal[0];
    float p = 0.f;
    if (i < NN) {
        if (ready[i] > 0) p = expf(logits[i] - M);
        d_out[i] = p;
    }
    float s = p;
#pragma unroll
    for (int off = 32; off > 0; off >>= 1) s += __shfl_xor(s, off, 64);
    if ((t & 63) == 0) warr[t >> 6] = s;
    __syncthreads();
    if (t == 0) atomicAdd(esum, warr[0] + warr[1] + warr[2] + warr[3]);
}

// ---------- normalize ----------
__global__ void k_scale(const float* __restrict__ esum, const float* __restrict__ scal,
                        float* __restrict__ d_out) {
    int i = blockIdx.x * blockDim.x + threadIdx.x;
    float inv = 1.0f / (esum[0] + scal[1]);
    if (i < NN) d_out[i] *= inv;
    else if (i == NN) d_out[NN] = scal[1] * inv;
}

extern "C" void kernel_launch(void* const* d_in, const int* in_sizes, int n_in,
                              void* d_out, int out_size, void* d_ws, size_t ws_size,
                              hipStream_t stream) {
    const float* x      = (const float*)d_in[0];
    const int*   edges  = (const int*)d_in[1];
    const float* eattr  = (const float*)d_in[2];
    const int*   ready  = (const int*)d_in[3];
    const float* pe     = (const float*)d_in[4];
    const float* gcn_w  = (const float*)d_in[5];
    const float* gcn_b  = (const float*)d_in[6];
    const float* mlp_w1 = (const float*)d_in[7];
    const float* mlp_b1 = (const float*)d_in[8];
    const float* mlp_w2 = (const float*)d_in[9];
    const float* mlp_b2 = (const float*)d_in[10];
    const float* val_w  = (const float*)d_in[11];
    const float* val_b  = (const float*)d_in[12];
    const float* cl_w   = (const float*)d_in[13];
    const float* cl_b   = (const float*)d_in[14];
    const float* pw1    = (const float*)d_in[15];
    const float* pb1    = (const float*)d_in[16];
    const float* pw2    = (const float*)d_in[17];
    const float* pb2    = (const float*)d_in[18];

    const int* rows = edges;
    const int* cols = edges + EE;

    // workspace layout (~72 MB)
    float* ws      = (float*)d_ws;
    float* dis     = ws;                          // N
    float* logits  = ws + NN;                     // N
    int*   count   = (int*)(ws + 2 * (size_t)NN); // N
    int*   base    = count + NN;                  // N+1 (sentinel)
    int*   bsum    = base + NN + 1;               // 256
    float* bufB    = (float*)(bsum + 256 + 3);    // N*128 fp32 (gather out / gemm in)
    uchar* bufH    = (uchar*)(bufB + (size_t)NN * HH);   // N*128 fp8 (pre-scaled h')
    unsigned* csre = (unsigned*)(bufH + (size_t)NN * HH); // E x 4B packed (col<<15|ea15)
    float* meansum = (float*)(csre + EE);         // NREP*128
    unsigned* maxenc  = (unsigned*)(meansum + NREP * HH);  // NREP*128
    unsigned* lmaxenc = maxenc + NREP * HH;
    float* esum    = (float*)(lmaxenc + 1);
    float* scal    = esum + 1;                    // 2
    ushort* wt     = (ushort*)(scal + 2);         // 3*128*128 bf16 transposed weights

    // aliases (lifetime-disjoint):
    //  cnt (CC*N int = 12.8MB, used k_cnt..k_makeptr) aliases bufH (12.8MB, first written by mfma<0> later)
    //  fillptr (CC*N int = 12.8MB, used k_makeptr..k_fill) aliases bufB (first written by gather0 later)
    int* cnt     = (int*)bufH;
    int* fillptr = (int*)bufB;

    float* out = (float*)d_out;

    const int nb = (NN + 255) / 256;
    const int gb = (NN + 63) / 64;
    const int ab = (NN * 64 + 255) / 256;   // gather: wave per node
    const int cb = CC * 8;                  // cnt/fill: chunk x partition

    k_init<<<(NREP * HH + 255) / 256, 256, 0, stream>>>(meansum, maxenc, lmaxenc, esum);
    k_prep<<<(3 * HH * HH + 255) / 256, 256, 0, stream>>>(gcn_w, gcn_w + HH * HH, mlp_w1, wt);

    // CSR build (atomic-free histogram + LDS-ranked fill)
    k_cnt<<<cb, 256, 0, stream>>>(rows, cnt);
    k_rowsum<<<nb, 256, 0, stream>>>(cnt, count);
    k_scan1<<<NSCAN, 256, 0, stream>>>(count, base, bsum);
    k_scan2<<<1, 256, 0, stream>>>(bsum);
    k_scan3<<<nb, 256, 0, stream>>>(base, bsum);
    k_makeptr<<<nb, 256, 0, stream>>>(cnt, base, fillptr);
    k_fill<<<cb, 256, 0, stream>>>(rows, cols, eattr, fillptr, csre);
    k_degsum<<<nb, 256, 0, stream>>>(csre, base, dis);

    // layer 0
    k_mfma<0><<<gb, 256, 0, stream>>>(x, wt, bufH, dis, nullptr, nullptr, nullptr, nullptr,
                                      nullptr, nullptr, nullptr, nullptr, NN);
    k_gather<<<ab, 256, 0, stream>>>(bufH, csre, base, dis, gcn_b, bufB);

    // layer 1 (relu applied on staging of bufB)
    k_mfma<1><<<gb, 256, 0, stream>>>(bufB, wt + HH * HH, bufH, dis, nullptr, nullptr, nullptr,
                                      nullptr, nullptr, nullptr, nullptr, nullptr, NN);
    k_gather<<<ab, 256, 0, stream>>>(bufH, csre, base, dis, gcn_b + HH, bufB);

    // heads
    k_mfma<2><<<gb, 256, 0, stream>>>(bufB, wt + 2 * HH * HH, nullptr, nullptr, mlp_b1, mlp_w2,
                                      mlp_b2, ready, logits, meansum, maxenc, lmaxenc, NN);
    k_fin1<<<1, 256, 0, stream>>>(meansum, maxenc, lmaxenc, val_w, val_b, pe, cl_w, cl_b,
                                  pw1, pb1, pw2, pb2, scal, out);
    k_exp<<<nb, 256, 0, stream>>>(logits, ready, scal, out, esum);
    k_scale<<<(NN + 1 + 255) / 256, 256, 0, stream>>>(esum, scal, out);
}

// Round 11
// 443.558 us; speedup vs baseline: 1.3553x; 1.1514x over previous
//
#include <hip/hip_runtime.h>
#include <cstdint>

#define NN 100000
#define EE 1600000
#define HH 128
#define NREP 8
#define PSZ (NN / 8)                 // 12500 rows per partition
#define SS 64                        // sub-slices per partition
#define CAP 300000                   // per-partition bucket capacity (entries)
#define NBB 500                      // bucket blocks
#define BCH 3200                     // edges per bucket block (500*3200 = EE)
#define SCAN_CHUNK 512
#define NSCAN ((NN + SCAN_CHUNK - 1) / SCAN_CHUNK)   // 196

typedef unsigned long long u64;
typedef unsigned short ushort;
typedef unsigned char uchar;
typedef __attribute__((ext_vector_type(8))) short bf16x8;
typedef __attribute__((ext_vector_type(4))) float f32x4;
typedef __attribute__((ext_vector_type(2))) float f32x2;

// ---------- bf16 helpers (RNE, finite values) ----------
__device__ __forceinline__ ushort f2bf(float x) {
    union { float f; unsigned u; } v; v.f = x;
    unsigned r = v.u + 0x7fffu + ((v.u >> 16) & 1u);
    return (ushort)(r >> 16);
}
__device__ __forceinline__ float bf2f(unsigned h16) {
    union { unsigned u; float f; } v; v.u = h16 << 16; return v.f;
}

// ---------- fp8 e4m3 helpers (HW cvt) ----------
__device__ __forceinline__ uchar f2fp8(float a) {
    return (uchar)(__builtin_amdgcn_cvt_pk_fp8_f32(a, a, 0, false) & 0xff);
}
__device__ __forceinline__ void unpack8_fp8(uint2 q, float* v) {
    f32x2 a = __builtin_amdgcn_cvt_pk_f32_fp8(q.x, false);
    f32x2 b = __builtin_amdgcn_cvt_pk_f32_fp8(q.x, true);
    f32x2 c = __builtin_amdgcn_cvt_pk_f32_fp8(q.y, false);
    f32x2 d = __builtin_amdgcn_cvt_pk_f32_fp8(q.y, true);
    v[0] = a[0]; v[1] = a[1]; v[2] = b[0]; v[3] = b[1];
    v[4] = c[0]; v[5] = c[1]; v[6] = d[0]; v[7] = d[1];
}

// ---------- monotone float<->uint encoding for atomicMax on floats ----------
__device__ __forceinline__ unsigned encf(float f) {
    int b = __float_as_int(f);
    return (b >= 0) ? ((unsigned)b | 0x80000000u) : ~(unsigned)b;
}
__device__ __forceinline__ float decf(unsigned u) {
    return (u & 0x80000000u) ? __int_as_float((int)(u & 0x7fffffffu))
                             : __int_as_float((int)(~u));
}
#define ENC_NEG_INF 0x007FFFFFu  // encf(-inf)

// ---------- small init ----------
__global__ void k_init(float* __restrict__ meansum, unsigned* __restrict__ maxenc,
                       unsigned* __restrict__ lmaxenc, float* __restrict__ esum,
                       int* __restrict__ gtail) {
    int i = blockIdx.x * blockDim.x + threadIdx.x;
    if (i < NREP * HH) { meansum[i] = 0.f; maxenc[i] = ENC_NEG_INF; }
    if (i < 8) gtail[i] = 0;
    if (i == 0) { lmaxenc[0] = ENC_NEG_INF; esum[0] = 0.f; }
}

// ---------- pre-transpose weights to bf16 Wt[n][k] ----------
__global__ void k_prep(const float* __restrict__ w0, const float* __restrict__ w1,
                       const float* __restrict__ w2, ushort* __restrict__ wt) {
    int idx = blockIdx.x * blockDim.x + threadIdx.x;
    if (idx >= 3 * HH * HH) return;
    int mat = idx >> 14;
    int e = idx & 16383;
    int n = e >> 7, k = e & 127;
    const float* src = (mat == 0) ? w0 : (mat == 1) ? w1 : w2;
    wt[idx] = f2bf(src[k * HH + n]);
}

// ---------- bucket: split edges into 8 partition-major packed streams ----------
// entry: (rlocal << 32) | (col << 15) | q15
__global__ __launch_bounds__(256) void k_bucket(const int* __restrict__ rows,
                                                const int* __restrict__ cols,
                                                const float* __restrict__ ea,
                                                int* __restrict__ gtail,
                                                u64* __restrict__ ebuck) {
    __shared__ u64 buf[8][1024];   // 64 KB
    __shared__ int cnt8[8];
    __shared__ int rsv[8];
    int t = threadIdx.x;
    if (t < 8) cnt8[t] = 0;
    __syncthreads();
    int e0 = blockIdx.x * BCH;
    int e1 = e0 + BCH;
    for (int ebase = e0; ebase < e1; ebase += 1024) {
        int e = ebase + t * 4;
        if (e < e1) {
            int4 r4 = *(const int4*)(rows + e);
            int4 c4 = *(const int4*)(cols + e);
            float4 a4 = *(const float4*)(ea + e);
            int rr[4] = {r4.x, r4.y, r4.z, r4.w};
            int cc[4] = {c4.x, c4.y, c4.z, c4.w};
            float aa[4] = {a4.x, a4.y, a4.z, a4.w};
#pragma unroll
            for (int j = 0; j < 4; ++j) {
                int p = rr[j] / PSZ;
                int rl = rr[j] - p * PSZ;
                unsigned q = (unsigned)(aa[j] * 32767.0f + 0.5f);
                u64 en = ((u64)rl << 32) | (u64)(((unsigned)cc[j] << 15) | q);
                int idx = atomicAdd(&cnt8[p], 1);
                buf[p][idx] = en;
            }
        }
        __syncthreads();
        if (t < 8) rsv[t] = atomicAdd(&gtail[t], cnt8[t]);
        __syncthreads();
#pragma unroll
        for (int p = 0; p < 8; ++p) {
            int nn = cnt8[p], oo = rsv[p];
            u64* dst = ebuck + (size_t)p * CAP + oo;
            for (int j = t; j < nn; j += 256) dst[j] = buf[p][j];
        }
        __syncthreads();
        if (t < 8) cnt8[t] = 0;
        __syncthreads();
    }
}

// ---------- count: per-(partition,sub-slice) LDS u16x2 histogram ----------
__global__ __launch_bounds__(256) void k_cnt2(const u64* __restrict__ ebuck,
                                              const int* __restrict__ gtail,
                                              int* __restrict__ cnt) {
    __shared__ unsigned h32[PSZ / 2];   // 25 KB
    int b = blockIdx.x;
    int s = b >> 3, p = b & 7;
    for (int j = threadIdx.x; j < PSZ / 2; j += 256) h32[j] = 0;
    __syncthreads();
    int pc = gtail[p];
    int len = (pc + SS - 1) / SS;
    int lo = s * len, hi = min(lo + len, pc);
    const u64* src = ebuck + (size_t)p * CAP;
    for (int i = lo + threadIdx.x; i < hi; i += 256) {
        int rl = (int)(src[i] >> 32);
        atomicAdd(&h32[rl >> 1], (rl & 1) ? 0x10000u : 1u);
    }
    __syncthreads();
    int* dst = cnt + (size_t)(p * SS + s) * PSZ;
    for (int j = threadIdx.x; j < PSZ / 2; j += 256) {
        unsigned v = h32[j];
        ((int2*)dst)[j] = make_int2((int)(v & 0xffffu), (int)(v >> 16));
    }
}

// ---------- count[r] = sum over sub-slices ----------
__global__ void k_rowsum(const int* __restrict__ cnt, int* __restrict__ count) {
    int r = blockIdx.x * blockDim.x + threadIdx.x;
    if (r >= NN) return;
    int p = r / PSZ, rl = r - p * PSZ;
    int s = 0;
#pragma unroll 8
    for (int c = 0; c < SS; ++c) s += cnt[(size_t)(p * SS + c) * PSZ + rl];
    count[r] = s;
}

// ---------- exclusive scan of count -> base ----------
__global__ void k_scan1(const int* __restrict__ cnt, int* __restrict__ out,
                        int* __restrict__ bsum) {
    int b = blockIdx.x, t = threadIdx.x;
    int i0 = b * SCAN_CHUNK + t * 2;
    int c0 = (i0 < NN) ? cnt[i0] : 0;
    int c1 = (i0 + 1 < NN) ? cnt[i0 + 1] : 0;
    int s = c0 + c1;
    int lane = t & 63, w = t >> 6;
    int v = s;
#pragma unroll
    for (int off = 1; off < 64; off <<= 1) {
        int u = __shfl_up(v, off, 64);
        if (lane >= off) v += u;
    }
    __shared__ int wsum[4];
    if (lane == 63) wsum[w] = v;
    __syncthreads();
    int wadd = 0;
    for (int j = 0; j < w; ++j) wadd += wsum[j];
    int incl = v + wadd;
    int excl = incl - s;
    if (i0 < NN) out[i0] = excl;
    if (i0 + 1 < NN) out[i0 + 1] = excl + c0;
    if (t == 255) bsum[b] = incl;
}

__global__ void k_scan2(int* __restrict__ bsum) {
    __shared__ int tmp[256];
    int t = threadIdx.x;
    int v = (t < NSCAN) ? bsum[t] : 0;
    tmp[t] = v;
    __syncthreads();
    for (int off = 1; off < 256; off <<= 1) {
        int u = (t >= off) ? tmp[t - off] : 0;
        __syncthreads();
        tmp[t] += u;
        __syncthreads();
    }
    if (t < NSCAN) bsum[t] = tmp[t] - v;  // exclusive
}

__global__ void k_scan3(int* __restrict__ out, const int* __restrict__ bsum) {
    int i = blockIdx.x * blockDim.x + threadIdx.x;
    if (i < NN) out[i] += bsum[i / SCAN_CHUNK];
    if (i == 0) out[NN] = EE;   // sentinel
}

// ---------- per-(partition,sub-slice,row) fill starts ----------
__global__ void k_makeptr(const int* __restrict__ cnt, const int* __restrict__ base,
                          int* __restrict__ fillptr) {
    int r = blockIdx.x * blockDim.x + threadIdx.x;
    if (r >= NN) return;
    int p = r / PSZ, rl = r - p * PSZ;
    int acc = base[r];
#pragma unroll 8
    for (int c = 0; c < SS; ++c) {
        fillptr[(size_t)(p * SS + c) * PSZ + rl] = acc;
        acc += cnt[(size_t)(p * SS + c) * PSZ + rl];
    }
}

// ---------- fill CSR from bucketed streams; LDS slot counters; XCD-local writes ----------
__global__ __launch_bounds__(256) void k_fill2(const u64* __restrict__ ebuck,
                                               const int* __restrict__ gtail,
                                               const int* __restrict__ fillptr,
                                               unsigned* __restrict__ csre) {
    __shared__ int nxt[PSZ];   // 50 KB
    int b = blockIdx.x;
    int s = b >> 3, p = b & 7;
    const int* fsrc = fillptr + (size_t)(p * SS + s) * PSZ;
    for (int j = threadIdx.x; j < PSZ; j += 256) nxt[j] = fsrc[j];
    __syncthreads();
    int pc = gtail[p];
    int len = (pc + SS - 1) / SS;
    int lo = s * len, hi = min(lo + len, pc);
    const u64* src = ebuck + (size_t)p * CAP;
    for (int i = lo + threadIdx.x; i < hi; i += 256) {
        u64 en = src[i];
        int rl = (int)(en >> 32);
        int slot = atomicAdd(&nxt[rl], 1);
        csre[slot] = (unsigned)(en & 0xffffffffu);
    }
}

// ---------- deg from csre segment sums -> dis ----------
__global__ void k_degsum(const unsigned* __restrict__ csre, const int* __restrict__ base,
                         float* __restrict__ dis) {
    int r = blockIdx.x * blockDim.x + threadIdx.x;
    if (r >= NN) return;
    int lo = base[r], hi = base[r + 1];
    float s = 0.f;
    for (int e = lo; e < hi; ++e) s += (float)(csre[e] & 0x7fffu);
    dis[r] = rsqrtf(1.0f + s * (1.0f / 32767.0f));
}

// ---------- gather: wave per node, 4 groups x 16 lanes; fp8 rows in, bf16 out ----------
__global__ __launch_bounds__(256) void k_gather(const uchar* __restrict__ hW,
                                                const unsigned* __restrict__ csre,
                                                const int* __restrict__ base,
                                                const float* __restrict__ dis,
                                                const float* __restrict__ bias,
                                                ushort* __restrict__ agg) {
    int node = (blockIdx.x * 256 + threadIdx.x) >> 6;
    if (node >= NN) return;
    int lane = threadIdx.x & 63;
    int g = lane >> 4, l = lane & 15;
    int f = l * 8;                     // byte offset within 128B row
    int lo = base[node], hi = base[node + 1];
    float disn = dis[node];
    float wk = disn * (1.0f / 32767.0f);
    const unsigned SELF = (unsigned)node << 15;  // weight bits = 0
    float acc[8];
#pragma unroll
    for (int j = 0; j < 8; ++j) acc[j] = 0.f;
    if (g == 0) {  // self-loop
        uint2 q = *(const uint2*)(hW + (size_t)node * HH + f);
        float v[8]; unpack8_fp8(q, v);
#pragma unroll
        for (int j = 0; j < 8; ++j) acc[j] = disn * v[j];
    }
    for (int eb = lo + g; eb < hi; eb += 16) {
        unsigned pp[4];
#pragma unroll
        for (int j = 0; j < 4; ++j) {
            int e = eb + j * 4;
            pp[j] = (e < hi) ? csre[e] : SELF;
        }
        uint2 qq[4];
#pragma unroll
        for (int j = 0; j < 4; ++j)
            qq[j] = *(const uint2*)(hW + (size_t)(pp[j] >> 15) * HH + f);
#pragma unroll
        for (int j = 0; j < 4; ++j) {
            float w = (float)(pp[j] & 0x7fffu) * wk;
            float v[8]; unpack8_fp8(qq[j], v);
#pragma unroll
            for (int k = 0; k < 8; ++k) acc[k] += w * v[k];
        }
    }
#pragma unroll
    for (int j = 0; j < 8; ++j) {
        acc[j] += __shfl_xor(acc[j], 16, 64);
        acc[j] += __shfl_xor(acc[j], 32, 64);
    }
    if (g == 0) {
        float4 b0 = *(const float4*)(bias + f);
        float4 b1 = *(const float4*)(bias + f + 4);
        ushort o[8];
        o[0] = f2bf(acc[0] + b0.x); o[1] = f2bf(acc[1] + b0.y);
        o[2] = f2bf(acc[2] + b0.z); o[3] = f2bf(acc[3] + b0.w);
        o[4] = f2bf(acc[4] + b1.x); o[5] = f2bf(acc[5] + b1.y);
        o[6] = f2bf(acc[6] + b1.z); o[7] = f2bf(acc[7] + b1.w);
        *(uint4*)(agg + (size_t)node * HH + f) = *(uint4*)o;
    }
}

// ---------- MFMA GEMM: 64x128 tile, K=128, bf16 inputs, fp32 acc ----------
// MODE 0: A fp32 (x), no relu    -> C_fp8 = fp8(dis*(A@W))
// MODE 1: A bf16, relu           -> C_fp8 = fp8(dis*(relu(A)@W))
// MODE 2: A bf16, relu; heads: logits + mean/masked-max
template <int MODE>
__global__ __launch_bounds__(256) void k_mfma(const void* __restrict__ Ain,
                                              const ushort* __restrict__ Wt,
                                              uchar* __restrict__ C,
                                              const float* __restrict__ dis,
                                              const float* __restrict__ b1,
                                              const float* __restrict__ w2v,
                                              const float* __restrict__ b2,
                                              const int* __restrict__ ready,
                                              float* __restrict__ logits,
                                              float* __restrict__ meansum,
                                              unsigned* __restrict__ maxenc,
                                              unsigned* __restrict__ lmaxenc, int n) {
    __shared__ ushort As[64 * HH];   // 16 KB, swizzled: elem(m,k) at m*128 + ((k>>3)^(m&15))*8 + (k&7)
    __shared__ int rdy[64];
    __shared__ unsigned slmax;
    const int t = threadIdx.x;
    const int rb = blockIdx.x * 64;
    if (MODE == 2) {
        if (t < 64) rdy[t] = (rb + t < n) ? ready[rb + t] : 0;
        if (t == 0) slmax = ENC_NEG_INF;
    }
    // stage A tile (bf16, swizzled)
#pragma unroll
    for (int i = 0; i < 4; ++i) {
        int m = i * 16 + (t >> 4);
        int k = (t & 15) * 8;
        ushort pk[8];
        if (MODE == 0) {
            const float* Af = (const float*)Ain;
            float4 v0 = make_float4(0.f, 0.f, 0.f, 0.f), v1 = v0;
            if (rb + m < n) {
                const float* src = Af + (size_t)(rb + m) * HH + k;
                v0 = *(const float4*)src;
                v1 = *(const float4*)(src + 4);
            }
            pk[0] = f2bf(v0.x); pk[1] = f2bf(v0.y); pk[2] = f2bf(v0.z); pk[3] = f2bf(v0.w);
            pk[4] = f2bf(v1.x); pk[5] = f2bf(v1.y); pk[6] = f2bf(v1.z); pk[7] = f2bf(v1.w);
        } else {
            const ushort* Au = (const ushort*)Ain;
            uint4 q = make_uint4(0, 0, 0, 0);
            if (rb + m < n) q = *(const uint4*)(Au + (size_t)(rb + m) * HH + k);
            *(uint4*)pk = q;
#pragma unroll
            for (int j = 0; j < 8; ++j) pk[j] = (pk[j] & 0x8000) ? (ushort)0 : pk[j];  // bf16 relu
        }
        int gsw = (t & 15) ^ (m & 15);
        *(uint4*)(As + m * HH + gsw * 8) = *(uint4*)pk;
    }
    __syncthreads();

    const int wave = t >> 6, lane = t & 63;
    const int cl = lane & 15;       // column-within-tile / A row
    const int kq = lane >> 4;       // k quad
    const int m0 = wave * 16;

    f32x4 acc[8];
#pragma unroll
    for (int c = 0; c < 8; ++c) acc[c] = (f32x4){0.f, 0.f, 0.f, 0.f};

    const int am = m0 + cl;
#pragma unroll
    for (int kk = 0; kk < 4; ++kk) {
        int g = kk * 4 + kq;
        bf16x8 a = *(const bf16x8*)(As + am * HH + ((g ^ cl) * 8));
#pragma unroll
        for (int c = 0; c < 8; ++c) {
            bf16x8 b = *(const bf16x8*)(Wt + (size_t)(c * 16 + cl) * HH + kk * 32 + kq * 8);
            acc[c] = __builtin_amdgcn_mfma_f32_16x16x32_bf16(a, b, acc[c], 0, 0, 0);
        }
    }

    if (MODE < 2) {
        // store C fp8 pre-scaled by dis[row]: D row = m0 + kq*4 + r, col = c*16 + cl
#pragma unroll
        for (int r = 0; r < 4; ++r) {
            int row = rb + m0 + kq * 4 + r;
            if (row < n) {
                float dsc = dis[row];
#pragma unroll
                for (int c = 0; c < 8; ++c)
                    C[(size_t)row * HH + c * 16 + cl] = f2fp8(acc[c][r] * dsc);
            }
        }
    } else {
        // heads epilogue
        float b1c[8], w2c[8];
#pragma unroll
        for (int c = 0; c < 8; ++c) { b1c[c] = b1[c * 16 + cl]; w2c[c] = w2v[c * 16 + cl]; }
        const float b2s = b2[0];
        unsigned mylmax = ENC_NEG_INF;
#pragma unroll
        for (int r = 0; r < 4; ++r) {
            float s = 0.f;
#pragma unroll
            for (int c = 0; c < 8; ++c)
                s += fmaxf(acc[c][r] + b1c[c], 0.f) * w2c[c];
            s += __shfl_xor(s, 1, 64);
            s += __shfl_xor(s, 2, 64);
            s += __shfl_xor(s, 4, 64);
            s += __shfl_xor(s, 8, 64);
            if (cl == 0) {
                int rloc = m0 + kq * 4 + r;
                int row = rb + rloc;
                if (row < n) {
                    float lg = s + b2s;
                    logits[row] = lg;
                    if (rdy[rloc] > 0) {
                        unsigned e = encf(lg);
                        if (e > mylmax) mylmax = e;
                    }
                }
            }
        }
        if (cl == 0 && mylmax != ENC_NEG_INF) atomicMax(&slmax, mylmax);

        // mean / masked-max of h = relu(A) (bf16 tile), per feature
        int lim = min(64, n - rb);
        if (t < HH) {
            int f = t, gf = f >> 3, fo = f & 7;
            float sum = 0.f, mx = -3.4e38f;
            for (int m = 0; m < lim; ++m) {
                float v = bf2f(As[m * HH + ((gf ^ (m & 15)) * 8) + fo]);
                sum += v;
                if (rdy[m] > 0) mx = fmaxf(mx, v);
            }
            int rep = blockIdx.x & (NREP - 1);
            atomicAdd(&meansum[rep * HH + f], sum);
            if (mx > -3.0e38f) atomicMax(&maxenc[rep * HH + f], encf(mx));
        }
        __syncthreads();
        if (t == 0 && slmax != ENC_NEG_INF) atomicMax(lmaxenc, slmax);
    }
}

// ---------- small finalize: fc, pass-MLP, v, global max M ----------
__global__ void k_fin1(const float* __restrict__ meansum, const unsigned* __restrict__ maxenc,
                       const unsigned* __restrict__ lmaxenc,
                       const float* __restrict__ val_w, const float* __restrict__ val_b,
                       const float* __restrict__ pe, const float* __restrict__ cl_w,
                       const float* __restrict__ cl_b, const float* __restrict__ pw1,
                       const float* __restrict__ pb1, const float* __restrict__ pw2,
                       const float* __restrict__ pb2, float* __restrict__ scal,
                       float* __restrict__ d_out) {
    __shared__ float xp[144];
    __shared__ float msum[HH];
    __shared__ float zp[HH];
    int t = threadIdx.x;
    if (t < HH) {
        float s = 0.f;
        unsigned mx = ENC_NEG_INF;
#pragma unroll
        for (int r = 0; r < NREP; ++r) {
            s += meansum[r * HH + t];
            unsigned e = maxenc[r * HH + t];
            if (e > mx) mx = e;
        }
        msum[t] = s;
        xp[t] = decf(mx);
    } else if (t < 144) {
        int c = t - HH;
        float s = cl_b[c];
        for (int k = 0; k < 30; ++k) s += pe[k] * cl_w[k * 16 + c];
        xp[t] = s;
    }
    __syncthreads();
    if (t < HH) {
        float s = pb1[t];
        for (int k = 0; k < 144; ++k) s += xp[k] * pw1[k * HH + t];
        zp[t] = fmaxf(s, 0.f);
    }
    __syncthreads();
    if (t < 64) {
        float s1 = zp[t] * pw2[t] + zp[t + 64] * pw2[t + 64];
        float s2 = msum[t] * val_w[t] + msum[t + 64] * val_w[t + 64];
#pragma unroll
        for (int off = 32; off > 0; off >>= 1) {
            s1 += __shfl_xor(s1, off, 64);
            s2 += __shfl_xor(s2, off, 64);
        }
        if (t == 0) {
            float xpass = s1 + pb2[0];
            float v = s2 * (1.0f / NN) + val_b[0];
            float M = fmaxf(decf(lmaxenc[0]), xpass);
            scal[0] = M;
            scal[1] = expf(xpass - M);
            d_out[NN + 1] = v;
        }
    }
}

// ---------- exp pass: unnormalized probs + sum ----------
__global__ __launch_bounds__(256) void k_exp(const float* __restrict__ logits,
                                             const int* __restrict__ ready,
                                             const float* __restrict__ scal,
                                             float* __restrict__ d_out,
                                             float* __restrict__ esum) {
    __shared__ float warr[4];
    int t = threadIdx.x;
    int i = blockIdx.x * 256 + t;
    float M = scal[0];
    float p = 0.f;
    if (i < NN) {
        if (ready[i] > 0) p = expf(logits[i] - M);
        d_out[i] = p;
    }
    float s = p;
#pragma unroll
    for (int off = 32; off > 0; off >>= 1) s += __shfl_xor(s, off, 64);
    if ((t & 63) == 0) warr[t >> 6] = s;
    __syncthreads();
    if (t == 0) atomicAdd(esum, warr[0] + warr[1] + warr[2] + warr[3]);
}

// ---------- normalize ----------
__global__ void k_scale(const float* __restrict__ esum, const float* __restrict__ scal,
                        float* __restrict__ d_out) {
    int i = blockIdx.x * blockDim.x + threadIdx.x;
    float inv = 1.0f / (esum[0] + scal[1]);
    if (i < NN) d_out[i] *= inv;
    else if (i == NN) d_out[NN] = scal[1] * inv;
}

extern "C" void kernel_launch(void* const* d_in, const int* in_sizes, int n_in,
                              void* d_out, int out_size, void* d_ws, size_t ws_size,
                              hipStream_t stream) {
    const float* x      = (const float*)d_in[0];
    const int*   edges  = (const int*)d_in[1];
    const float* eattr  = (const float*)d_in[2];
    const int*   ready  = (const int*)d_in[3];
    const float* pe     = (const float*)d_in[4];
    const float* gcn_w  = (const float*)d_in[5];
    const float* gcn_b  = (const float*)d_in[6];
    const float* mlp_w1 = (const float*)d_in[7];
    const float* mlp_b1 = (const float*)d_in[8];
    const float* mlp_w2 = (const float*)d_in[9];
    const float* mlp_b2 = (const float*)d_in[10];
    const float* val_w  = (const float*)d_in[11];
    const float* val_b  = (const float*)d_in[12];
    const float* cl_w   = (const float*)d_in[13];
    const float* cl_b   = (const float*)d_in[14];
    const float* pw1    = (const float*)d_in[15];
    const float* pb1    = (const float*)d_in[16];
    const float* pw2    = (const float*)d_in[17];
    const float* pb2    = (const float*)d_in[18];

    const int* rows = edges;
    const int* cols = edges + EE;

    // workspace carving (256B-aligned slices), ~92 MB
    char* P = (char*)d_ws;
    size_t off = 0;
    auto carve = [&](size_t bytes) {
        off = (off + 255) & ~(size_t)255;
        void* p = P + off;
        off += bytes;
        return p;
    };
    float* dis     = (float*)carve(NN * 4);
    float* logits  = (float*)carve(NN * 4);
    int*   count   = (int*)carve(NN * 4);
    int*   base    = (int*)carve((NN + 1) * 4);
    int*   bsum    = (int*)carve(256 * 4);
    ushort* bufB   = (ushort*)carve((size_t)NN * HH * 2);   // bf16 (gather out / gemm in)
    uchar* bufH    = (uchar*)carve((size_t)NN * HH);        // fp8 (gemm out / gather in)
    unsigned* csre = (unsigned*)carve((size_t)EE * 4);      // packed (col<<15|ea15)
    u64*   ebuck   = (u64*)carve((size_t)8 * CAP * 8);      // partition-major streams
    int*   fillptr = (int*)carve((size_t)8 * SS * PSZ * 4);
    float* meansum = (float*)carve(NREP * HH * 4);
    unsigned* maxenc = (unsigned*)carve(NREP * HH * 4);
    unsigned* lmaxenc = (unsigned*)carve(4);
    float* esum    = (float*)carve(4);
    float* scal    = (float*)carve(8);
    int*   gtail   = (int*)carve(8 * 4);
    ushort* wt     = (ushort*)carve(3 * HH * HH * 2);

    // alias (lifetime-disjoint): cnt (8*SS*PSZ int = 25.6MB, used k_cnt2..k_makeptr)
    // aliases bufB (25.6MB, first written by k_gather after fill2)
    int* cnt = (int*)bufB;

    float* out = (float*)d_out;

    const int nb = (NN + 255) / 256;
    const int gb = (NN + 63) / 64;
    const int ab = (NN * 64 + 255) / 256;   // gather: wave per node
    const int pb = 8 * SS;                  // cnt2/fill2 blocks

    k_init<<<(NREP * HH + 255) / 256, 256, 0, stream>>>(meansum, maxenc, lmaxenc, esum, gtail);
    k_prep<<<(3 * HH * HH + 255) / 256, 256, 0, stream>>>(gcn_w, gcn_w + HH * HH, mlp_w1, wt);

    // CSR build: bucket -> count -> scan -> fill (all coalesced, single-owner lines)
    k_bucket<<<NBB, 256, 0, stream>>>(rows, cols, eattr, gtail, ebuck);
    k_cnt2<<<pb, 256, 0, stream>>>(ebuck, gtail, cnt);
    k_rowsum<<<nb, 256, 0, stream>>>(cnt, count);
    k_scan1<<<NSCAN, 256, 0, stream>>>(count, base, bsum);
    k_scan2<<<1, 256, 0, stream>>>(bsum);
    k_scan3<<<nb, 256, 0, stream>>>(base, bsum);
    k_makeptr<<<nb, 256, 0, stream>>>(cnt, base, fillptr);
    k_fill2<<<pb, 256, 0, stream>>>(ebuck, gtail, fillptr, csre);
    k_degsum<<<nb, 256, 0, stream>>>(csre, base, dis);

    // layer 0
    k_mfma<0><<<gb, 256, 0, stream>>>(x, wt, bufH, dis, nullptr, nullptr, nullptr, nullptr,
                                      nullptr, nullptr, nullptr, nullptr, NN);
    k_gather<<<ab, 256, 0, stream>>>(bufH, csre, base, dis, gcn_b, bufB);

    // layer 1 (bf16 relu on staging)
    k_mfma<1><<<gb, 256, 0, stream>>>(bufB, wt + HH * HH, bufH, dis, nullptr, nullptr, nullptr,
                                      nullptr, nullptr, nullptr, nullptr, nullptr, NN);
    k_gather<<<ab, 256, 0, stream>>>(bufH, csre, base, dis, gcn_b + HH, bufB);

    // heads
    k_mfma<2><<<gb, 256, 0, stream>>>(bufB, wt + 2 * HH * HH, nullptr, nullptr, mlp_b1, mlp_w2,
                                      mlp_b2, ready, logits, meansum, maxenc, lmaxenc, NN);
    k_fin1<<<1, 256, 0, stream>>>(meansum, maxenc, lmaxenc, val_w, val_b, pe, cl_w, cl_b,
                                  pw1, pb1, pw2, pb2, scal, out);
    k_exp<<<nb, 256, 0, stream>>>(logits, ready, scal, out, esum);
    k_scale<<<(NN + 1 + 255) / 256, 256, 0, stream>>>(esum, scal, out);
}